// Round 1
// baseline (8775.147 us; speedup 1.0000x reference)
//
#include <hip/hip_runtime.h>

// ---------------------------------------------------------------------------
// StructuralGNN: GCN -> SAGE -> GAT(2 heads) -> Linear on N=50k, E=1.6M, D=128
// All fp32. Edge aggregation via native f32 atomics (unsafeAtomicAdd).
// ---------------------------------------------------------------------------

static __device__ __forceinline__ float leaky02(float x) {
    return x > 0.f ? x : 0.2f * x;
}
// monotone float -> uint encoding for atomicMax on floats
static __device__ __forceinline__ unsigned fenc(float f) {
    unsigned u = __float_as_uint(f);
    return (u & 0x80000000u) ? ~u : (u | 0x80000000u);
}
static __device__ __forceinline__ float fdec(unsigned e) {
    unsigned u = (e & 0x80000000u) ? (e ^ 0x80000000u) : ~e;
    return __uint_as_float(u);
}
static __device__ __forceinline__ void atomAddF(float* p, float v) {
    unsafeAtomicAdd(p, v);   // native global_atomic_add_f32 on gfx950
}

// ---------------------------------------------------------------------------
__global__ void fill_f32(float* __restrict__ p, float v, int n) {
    int i = blockIdx.x * blockDim.x + threadIdx.x;
    if (i < n) p[i] = v;
}

__global__ void deg_edges(const int* __restrict__ dst, float* __restrict__ deg, int E) {
    int e = blockIdx.x * blockDim.x + threadIdx.x;
    if (e < E) atomAddF(&deg[dst[e]], 1.0f);
}

__global__ void norm_node(const float* __restrict__ deg, float* __restrict__ dinv,
                          float* __restrict__ icnt, int n) {
    int i = blockIdx.x * blockDim.x + threadIdx.x;
    if (i < n) {
        float d = deg[i];                 // >= 1 (self loop)
        dinv[i] = rsqrtf(d);
        icnt[i] = 1.0f / fmaxf(d - 1.0f, 1.0f);   // SAGE cnt = deg - 1
    }
}

// ---------------------------------------------------------------------------
// C[n x ncC slice] = act( A1*scale @ W1 + A2[idx] @ W2 + bias ), K=128 per input
// Block: 256 threads computes 64 rows x 128 cols; micro-tile 4x8.
template<bool HAS_A2, bool HAS_SCALE, bool RELU, bool HAS_BIAS, bool HAS_IDX>
__global__ __launch_bounds__(256)
void gemm_k128(const float* __restrict__ A1, const float* __restrict__ W1,
               const float* __restrict__ A2, const float* __restrict__ W2,
               const int* __restrict__ idx2,
               const float* __restrict__ scale1, const float* __restrict__ bias,
               float* __restrict__ C, int nrows, int ncW, int ncC)
{
    __shared__ float As[64][33];
    __shared__ float Ws[32][128];
    const int t = threadIdx.x;
    const int tc = t & 15;        // 16 col groups * 8 cols
    const int tr = t >> 4;        // 16 row groups * 4 rows
    const int row0 = blockIdx.x * 64;
    const int colOff = blockIdx.y * 128;

    float acc[4][8];
#pragma unroll
    for (int i = 0; i < 4; ++i)
#pragma unroll
        for (int j = 0; j < 8; ++j) acc[i][j] = 0.f;

    const int npass = HAS_A2 ? 2 : 1;
    for (int p = 0; p < npass; ++p) {
        const float* A = (p == 0) ? A1 : A2;
        const float* W = (p == 0) ? W1 : W2;
        for (int kt = 0; kt < 4; ++kt) {
            // stage A: 64 rows x 32 cols
#pragma unroll
            for (int l = t; l < 512; l += 256) {
                int r = l >> 3, c4 = (l & 7) << 2;
                int row = row0 + r; if (row >= nrows) row = nrows - 1;
                int arow = row;
                if (p == 1 && HAS_IDX) arow = idx2[row];
                float4 v = *(const float4*)(A + (size_t)arow * 128 + kt * 32 + c4);
                float s = 1.f;
                if (p == 0 && HAS_SCALE) s = scale1[row];
                As[r][c4 + 0] = v.x * s;
                As[r][c4 + 1] = v.y * s;
                As[r][c4 + 2] = v.z * s;
                As[r][c4 + 3] = v.w * s;
            }
            // stage W: 32 rows x 128 cols
#pragma unroll
            for (int l = t; l < 1024; l += 256) {
                int r = l >> 5, c4 = (l & 31) << 2;
                *(float4*)&Ws[r][c4] =
                    *(const float4*)(W + (size_t)(kt * 32 + r) * ncW + colOff + c4);
            }
            __syncthreads();
#pragma unroll
            for (int kk = 0; kk < 32; ++kk) {
                float a[4], w[8];
#pragma unroll
                for (int i = 0; i < 4; ++i) a[i] = As[tr * 4 + i][kk];
#pragma unroll
                for (int j = 0; j < 8; ++j) w[j] = Ws[kk][tc * 8 + j];
#pragma unroll
                for (int i = 0; i < 4; ++i)
#pragma unroll
                    for (int j = 0; j < 8; ++j)
                        acc[i][j] = fmaf(a[i], w[j], acc[i][j]);
            }
            __syncthreads();
        }
    }
#pragma unroll
    for (int i = 0; i < 4; ++i) {
        int row = row0 + tr * 4 + i;
        if (row < nrows) {
            float4 v0, v1;
            float vv[8];
#pragma unroll
            for (int j = 0; j < 8; ++j) {
                float v = acc[i][j];
                if (HAS_BIAS) v += bias[colOff + tc * 8 + j];
                if (RELU) v = fmaxf(v, 0.f);
                vv[j] = v;
            }
            v0 = make_float4(vv[0], vv[1], vv[2], vv[3]);
            v1 = make_float4(vv[4], vv[5], vv[6], vv[7]);
            float* cp = C + (size_t)row * ncC + colOff + tc * 8;
            *(float4*)cp = v0;
            *(float4*)(cp + 4) = v1;
        }
    }
}

// ---------------------------------------------------------------------------
// one wave per edge: acc[dst] += hW[src] * dinv[src]*dinv[dst]   (128 floats)
__global__ __launch_bounds__(256)
void gcn_scatter(const int* __restrict__ src, const int* __restrict__ dst,
                 const float* __restrict__ dinv, const float* __restrict__ hW,
                 float* __restrict__ acc, int E)
{
    int e = blockIdx.x * 4 + (threadIdx.x >> 6);
    if (e >= E) return;
    int lane = threadIdx.x & 63;
    int s = src[e], d = dst[e];
    float nm = dinv[s] * dinv[d];
    float2 v = ((const float2*)(hW + (size_t)s * 128))[lane];
    float* p = acc + (size_t)d * 128 + lane * 2;
    atomAddF(p, v.x * nm);
    atomAddF(p + 1, v.y * nm);
}

// h1 = relu(h1 + hW * dinv^2 + b)   (adds self-loop term)
__global__ void gcn_final(float* __restrict__ h1, const float* __restrict__ hW,
                          const float* __restrict__ dinv, const float* __restrict__ b,
                          int n)
{
    int t = blockIdx.x * blockDim.x + threadIdx.x;
    if (t >= n * 128) return;
    int i = t >> 7, c = t & 127;
    float di = dinv[i];
    h1[t] = fmaxf(h1[t] + hW[t] * di * di + b[c], 0.f);
}

// one wave per edge: agg[dst] += h1[src]
__global__ __launch_bounds__(256)
void sage_scatter(const int* __restrict__ src, const int* __restrict__ dst,
                  const float* __restrict__ h1, float* __restrict__ agg, int E)
{
    int e = blockIdx.x * 4 + (threadIdx.x >> 6);
    if (e >= E) return;
    int lane = threadIdx.x & 63;
    int s = src[e], d = dst[e];
    float2 v = ((const float2*)(h1 + (size_t)s * 128))[lane];
    float* p = agg + (size_t)d * 128 + lane * 2;
    atomAddF(p, v.x);
    atomAddF(p + 1, v.y);
}

// ---------------------------------------------------------------------------
// per-node attention logits: a_s[i][h] = <xW[i,h,:], att_src[h,:]>, same for dst
__global__ __launch_bounds__(256)
void att_node(const float* __restrict__ xW, const float* __restrict__ att_src,
              const float* __restrict__ att_dst, float* __restrict__ a_s,
              float* __restrict__ a_d, int n)
{
    int i = blockIdx.x * 4 + (threadIdx.x >> 6);
    if (i >= n) return;
    int lane = threadIdx.x & 63;
#pragma unroll
    for (int h = 0; h < 2; ++h) {
        float2 v  = ((const float2*)(xW + (size_t)i * 256 + h * 128))[lane];
        float2 s2 = ((const float2*)(att_src + h * 128))[lane];
        float2 d2 = ((const float2*)(att_dst + h * 128))[lane];
        float ps = v.x * s2.x + v.y * s2.y;
        float pd = v.x * d2.x + v.y * d2.y;
#pragma unroll
        for (int m = 32; m > 0; m >>= 1) {
            ps += __shfl_xor(ps, m, 64);
            pd += __shfl_xor(pd, m, 64);
        }
        if (lane == 0) { a_s[i * 2 + h] = ps; a_d[i * 2 + h] = pd; }
    }
}

// amax init with self-loop alpha (encoded)
__global__ void amax_init(const float* __restrict__ a_s, const float* __restrict__ a_d,
                          unsigned* __restrict__ amax, int n2)
{
    int t = blockIdx.x * blockDim.x + threadIdx.x;
    if (t < n2) amax[t] = fenc(leaky02(a_s[t] + a_d[t]));
}

__global__ void amax_edges(const int* __restrict__ src, const int* __restrict__ dst,
                           const float* __restrict__ a_s, const float* __restrict__ a_d,
                           unsigned* __restrict__ amax, int E)
{
    int e = blockIdx.x * blockDim.x + threadIdx.x;
    if (e >= E) return;
    int s = src[e], d = dst[e];
#pragma unroll
    for (int h = 0; h < 2; ++h) {
        float al = leaky02(a_s[s * 2 + h] + a_d[d * 2 + h]);
        atomicMax(&amax[d * 2 + h], fenc(al));
    }
}

// decode amax to float; seed asum with self-loop exp term
__global__ void amax_fin(float* __restrict__ amaxf, float* __restrict__ asum,
                         const float* __restrict__ a_s, const float* __restrict__ a_d,
                         int n2)
{
    int t = blockIdx.x * blockDim.x + threadIdx.x;
    if (t >= n2) return;
    unsigned e = ((unsigned*)amaxf)[t];
    float m = fdec(e);
    float self = leaky02(a_s[t] + a_d[t]);
    asum[t] = __expf(0.f) * expf(self - m);   // = expf(self - m)
    amaxf[t] = m;
}

__global__ void asum_edges(const int* __restrict__ src, const int* __restrict__ dst,
                           const float* __restrict__ a_s, const float* __restrict__ a_d,
                           const float* __restrict__ amax, float* __restrict__ asum, int E)
{
    int e = blockIdx.x * blockDim.x + threadIdx.x;
    if (e >= E) return;
    int s = src[e], d = dst[e];
#pragma unroll
    for (int h = 0; h < 2; ++h) {
        float al = leaky02(a_s[s * 2 + h] + a_d[d * 2 + h]);
        atomAddF(&asum[d * 2 + h], expf(al - amax[d * 2 + h]));
    }
}

// one wave per edge: gato[dst] += xW[src] * alpha   (256 floats, 2 heads)
__global__ __launch_bounds__(256)
void gat_scatter(const int* __restrict__ src, const int* __restrict__ dst,
                 const float* __restrict__ a_s, const float* __restrict__ a_d,
                 const float* __restrict__ amax, const float* __restrict__ asum,
                 const float* __restrict__ xW, float* __restrict__ gato, int E)
{
    int e = blockIdx.x * 4 + (threadIdx.x >> 6);
    if (e >= E) return;
    int lane = threadIdx.x & 63;
    int s = src[e], d = dst[e];
    float w[2];
#pragma unroll
    for (int h = 0; h < 2; ++h) {
        float al = leaky02(a_s[s * 2 + h] + a_d[d * 2 + h]);
        w[h] = expf(al - amax[d * 2 + h]) / (asum[d * 2 + h] + 1e-16f);
    }
    float4 v = ((const float4*)(xW + (size_t)s * 256))[lane];
    float wh = (lane < 32) ? w[0] : w[1];
    float* p = gato + (size_t)d * 256 + lane * 4;
    atomAddF(p + 0, v.x * wh);
    atomAddF(p + 1, v.y * wh);
    atomAddF(p + 2, v.z * wh);
    atomAddF(p + 3, v.w * wh);
}

// h3 = relu( 0.5*( (gato_h0 + xW_h0*w0self) + (gato_h1 + xW_h1*w1self) ) + b )
__global__ void gat_final(const float* __restrict__ gato, const float* __restrict__ xW,
                          const float* __restrict__ a_s, const float* __restrict__ a_d,
                          const float* __restrict__ amax, const float* __restrict__ asum,
                          const float* __restrict__ b_gat, float* __restrict__ h3, int n)
{
    int t = blockIdx.x * blockDim.x + threadIdx.x;
    if (t >= n * 128) return;
    int i = t >> 7, c = t & 127;
    float al0 = leaky02(a_s[i * 2 + 0] + a_d[i * 2 + 0]);
    float w0 = expf(al0 - amax[i * 2 + 0]) / (asum[i * 2 + 0] + 1e-16f);
    float al1 = leaky02(a_s[i * 2 + 1] + a_d[i * 2 + 1]);
    float w1 = expf(al1 - amax[i * 2 + 1]) / (asum[i * 2 + 1] + 1e-16f);
    float v0 = gato[(size_t)i * 256 + c]       + xW[(size_t)i * 256 + c]       * w0;
    float v1 = gato[(size_t)i * 256 + 128 + c] + xW[(size_t)i * 256 + 128 + c] * w1;
    h3[t] = fmaxf(0.5f * (v0 + v1) + b_gat[c], 0.f);
}

// final: out[N x 64] = h3 @ W_out + b_out, one wave per row
__global__ __launch_bounds__(256)
void out_gemm(const float* __restrict__ h3, const float* __restrict__ W,
              const float* __restrict__ b, float* __restrict__ out, int n)
{
    int r = blockIdx.x * 4 + (threadIdx.x >> 6);
    if (r >= n) return;
    int lane = threadIdx.x & 63;
    float acc = b[lane];
    const float* hp = h3 + (size_t)r * 128;
#pragma unroll 8
    for (int k = 0; k < 128; ++k)
        acc = fmaf(hp[k], W[k * 64 + lane], acc);
    out[(size_t)r * 64 + lane] = acc;
}

// ---------------------------------------------------------------------------
extern "C" void kernel_launch(void* const* d_in, const int* in_sizes, int n_in,
                              void* d_out, int out_size, void* d_ws, size_t ws_size,
                              hipStream_t stream)
{
    const float* x      = (const float*)d_in[0];
    const int*   ei     = (const int*)d_in[1];
    const int*   nidx   = (const int*)d_in[2];
    const float* emb    = (const float*)d_in[3];
    const float* W_gcn  = (const float*)d_in[4];
    const float* b_gcn  = (const float*)d_in[5];
    const float* W_sl   = (const float*)d_in[6];
    const float* W_sr   = (const float*)d_in[7];
    const float* b_sage = (const float*)d_in[8];
    const float* W_gat  = (const float*)d_in[9];
    const float* att_s  = (const float*)d_in[10];
    const float* att_d  = (const float*)d_in[11];
    const float* b_gat  = (const float*)d_in[12];
    const float* W_out  = (const float*)d_in[13];
    const float* b_out  = (const float*)d_in[14];
    float* out = (float*)d_out;

    const int n = in_sizes[0] / 128;
    const int E = in_sizes[1] / 2;
    const int* esrc = ei;
    const int* edst = ei + E;

    const size_t P = (size_t)n * 128;
    float* ws   = (float*)d_ws;
    float* hW   = ws;                // P   (later reused as h3)
    float* h1   = ws + P;            // P
    float* agg  = ws + 2 * P;        // P
    float* h2   = ws + 3 * P;        // P
    float* xW   = ws + 4 * P;        // 2P
    float* gato = ws + P;            // 2P  (reuses dead h1+agg)
    float* h3   = ws;                // P   (reuses dead hW)
    float* deg  = ws + 6 * P;        // n
    float* dinv = deg + n;           // n
    float* icnt = dinv + n;          // n
    float* a_s  = icnt + n;          // 2n
    float* a_d  = a_s + 2 * n;       // 2n
    float* amax = a_d + 2 * n;       // 2n (uint during max phase, then float)
    float* asum = amax + 2 * n;      // 2n

    const int TB = 256;
    int nblk_n     = (n + TB - 1) / TB;
    int nblk_e     = (E + TB - 1) / TB;
    int nblk_n2    = (2 * n + TB - 1) / TB;
    int nblk_nc    = (n * 128 + TB - 1) / TB;
    int nblk_wav_e = (E + 3) / 4;
    int nblk_wav_n = (n + 3) / 4;
    int gemm_rows  = (n + 63) / 64;

    // --- degrees (GCN deg includes self loop; SAGE cnt = deg-1) ---
    fill_f32<<<nblk_n, TB, 0, stream>>>(deg, 1.0f, n);
    deg_edges<<<nblk_e, TB, 0, stream>>>(edst, deg, E);
    norm_node<<<nblk_n, TB, 0, stream>>>(deg, dinv, icnt, n);

    // --- GCN ---
    hipMemsetAsync(h1, 0, 2 * P * sizeof(float), stream);   // h1 + agg
    gemm_k128<true, false, false, false, true><<<dim3(gemm_rows, 1), TB, 0, stream>>>(
        x, W_gcn, emb, W_gcn + 128 * 128, nidx, nullptr, nullptr, hW, n, 128, 128);
    gcn_scatter<<<nblk_wav_e, TB, 0, stream>>>(esrc, edst, dinv, hW, h1, E);
    gcn_final<<<nblk_nc, TB, 0, stream>>>(h1, hW, dinv, b_gcn, n);

    // --- SAGE ---
    sage_scatter<<<nblk_wav_e, TB, 0, stream>>>(esrc, edst, h1, agg, E);
    gemm_k128<true, true, true, true, false><<<dim3(gemm_rows, 1), TB, 0, stream>>>(
        agg, W_sl, h1, W_sr, nullptr, icnt, b_sage, h2, n, 128, 128);

    // --- GAT ---
    gemm_k128<false, false, false, false, false><<<dim3(gemm_rows, 2), TB, 0, stream>>>(
        h2, W_gat, nullptr, nullptr, nullptr, nullptr, nullptr, xW, n, 256, 256);
    att_node<<<nblk_wav_n, TB, 0, stream>>>(xW, att_s, att_d, a_s, a_d, n);
    amax_init<<<nblk_n2, TB, 0, stream>>>(a_s, a_d, (unsigned*)amax, 2 * n);
    amax_edges<<<nblk_e, TB, 0, stream>>>(esrc, edst, a_s, a_d, (unsigned*)amax, E);
    amax_fin<<<nblk_n2, TB, 0, stream>>>(amax, asum, a_s, a_d, 2 * n);
    asum_edges<<<nblk_e, TB, 0, stream>>>(esrc, edst, a_s, a_d, amax, asum, E);
    hipMemsetAsync(gato, 0, 2 * P * sizeof(float), stream);
    gat_scatter<<<nblk_wav_e, TB, 0, stream>>>(esrc, edst, a_s, a_d, amax, asum, xW, gato, E);
    gat_final<<<nblk_nc, TB, 0, stream>>>(gato, xW, a_s, a_d, amax, asum, b_gat, h3, n);

    // --- output ---
    out_gemm<<<nblk_wav_n, TB, 0, stream>>>(h3, W_out, b_out, out, n);
}

// Round 2
// 1233.401 us; speedup vs baseline: 7.1146x; 7.1146x over previous
//
#include <hip/hip_runtime.h>

// ---------------------------------------------------------------------------
// StructuralGNN: GCN -> SAGE -> GAT(2 heads) -> Linear on N=50k, E=1.6M, D=128
// Round 2: CSR-by-dst built per launch; all edge aggregation is gather-based
// (register accumulation, zero float atomics on feature rows).
// ---------------------------------------------------------------------------

static __device__ __forceinline__ float leaky02(float x) {
    return x > 0.f ? x : 0.2f * x;
}
static __device__ __forceinline__ void atomAddF(float* p, float v) {
    unsafeAtomicAdd(p, v);   // native global_atomic_add_f32 on gfx950
}

// ---------------------------------------------------------------------------
__global__ void fill_f32(float* __restrict__ p, float v, int n) {
    int i = blockIdx.x * blockDim.x + threadIdx.x;
    if (i < n) p[i] = v;
}

__global__ void deg_edges(const int* __restrict__ dst, float* __restrict__ deg, int E) {
    int e = blockIdx.x * blockDim.x + threadIdx.x;
    if (e < E) atomAddF(&deg[dst[e]], 1.0f);
}

__global__ void norm_node(const float* __restrict__ deg, float* __restrict__ dinv,
                          float* __restrict__ icnt, int n) {
    int i = blockIdx.x * blockDim.x + threadIdx.x;
    if (i < n) {
        float d = deg[i];                 // >= 1 (self loop)
        dinv[i] = rsqrtf(d);
        icnt[i] = 1.0f / fmaxf(d - 1.0f, 1.0f);   // SAGE cnt = deg - 1
    }
}

// single-block exclusive scan of edge counts ((int)deg - 1) -> rowptr[0..n]
__global__ __launch_bounds__(1024)
void scan_rowptr(const float* __restrict__ deg, int* __restrict__ rowptr, int n)
{
    __shared__ int tmp[1024];
    __shared__ int carry;
    const int t = threadIdx.x;
    if (t == 0) { carry = 0; rowptr[0] = 0; }
    __syncthreads();
    for (int base = 0; base < n; base += 1024) {
        int i = base + t;
        int v = (i < n) ? ((int)deg[i] - 1) : 0;
        tmp[t] = v;
        __syncthreads();
#pragma unroll
        for (int off = 1; off < 1024; off <<= 1) {
            int add = (t >= off) ? tmp[t - off] : 0;
            __syncthreads();
            tmp[t] += add;
            __syncthreads();
        }
        int incl = tmp[t] + carry;
        if (i < n) rowptr[i + 1] = incl;
        __syncthreads();
        if (t == 1023) carry = incl;
        __syncthreads();
    }
}

__global__ void csr_fill(const int* __restrict__ src, const int* __restrict__ dst,
                         const int* __restrict__ rowptr, int* __restrict__ fill,
                         int* __restrict__ csr, int E)
{
    int e = blockIdx.x * blockDim.x + threadIdx.x;
    if (e >= E) return;
    int d = dst[e];
    int pos = rowptr[d] + atomicAdd(&fill[d], 1);
    csr[pos] = src[e];
}

// ---------------------------------------------------------------------------
// C[n x ncC slice] = act( A1 @ W1 + A2[idx] @ W2 + bias ), K=128 per input
// Block: 256 threads computes 64 rows x 128 cols; micro-tile 4x8.
template<bool HAS_A2, bool RELU, bool HAS_BIAS, bool HAS_IDX>
__global__ __launch_bounds__(256)
void gemm_k128(const float* __restrict__ A1, const float* __restrict__ W1,
               const float* __restrict__ A2, const float* __restrict__ W2,
               const int* __restrict__ idx2, const float* __restrict__ bias,
               float* __restrict__ C, int nrows, int ncW, int ncC)
{
    __shared__ float As[64][33];
    __shared__ float Ws[32][128];
    const int t = threadIdx.x;
    const int tc = t & 15;        // 16 col groups * 8 cols
    const int tr = t >> 4;        // 16 row groups * 4 rows
    const int row0 = blockIdx.x * 64;
    const int colOff = blockIdx.y * 128;

    float acc[4][8];
#pragma unroll
    for (int i = 0; i < 4; ++i)
#pragma unroll
        for (int j = 0; j < 8; ++j) acc[i][j] = 0.f;

    const int npass = HAS_A2 ? 2 : 1;
    for (int p = 0; p < npass; ++p) {
        const float* A = (p == 0) ? A1 : A2;
        const float* W = (p == 0) ? W1 : W2;
        for (int kt = 0; kt < 4; ++kt) {
#pragma unroll
            for (int l = t; l < 512; l += 256) {
                int r = l >> 3, c4 = (l & 7) << 2;
                int row = row0 + r; if (row >= nrows) row = nrows - 1;
                int arow = row;
                if (p == 1 && HAS_IDX) arow = idx2[row];
                float4 v = *(const float4*)(A + (size_t)arow * 128 + kt * 32 + c4);
                As[r][c4 + 0] = v.x;
                As[r][c4 + 1] = v.y;
                As[r][c4 + 2] = v.z;
                As[r][c4 + 3] = v.w;
            }
#pragma unroll
            for (int l = t; l < 1024; l += 256) {
                int r = l >> 5, c4 = (l & 31) << 2;
                *(float4*)&Ws[r][c4] =
                    *(const float4*)(W + (size_t)(kt * 32 + r) * ncW + colOff + c4);
            }
            __syncthreads();
#pragma unroll
            for (int kk = 0; kk < 32; ++kk) {
                float a[4], w[8];
#pragma unroll
                for (int i = 0; i < 4; ++i) a[i] = As[tr * 4 + i][kk];
#pragma unroll
                for (int j = 0; j < 8; ++j) w[j] = Ws[kk][tc * 8 + j];
#pragma unroll
                for (int i = 0; i < 4; ++i)
#pragma unroll
                    for (int j = 0; j < 8; ++j)
                        acc[i][j] = fmaf(a[i], w[j], acc[i][j]);
            }
            __syncthreads();
        }
    }
#pragma unroll
    for (int i = 0; i < 4; ++i) {
        int row = row0 + tr * 4 + i;
        if (row < nrows) {
            float vv[8];
#pragma unroll
            for (int j = 0; j < 8; ++j) {
                float v = acc[i][j];
                if (HAS_BIAS) v += bias[colOff + tc * 8 + j];
                if (RELU) v = fmaxf(v, 0.f);
                vv[j] = v;
            }
            float* cp = C + (size_t)row * ncC + colOff + tc * 8;
            *(float4*)cp = make_float4(vv[0], vv[1], vv[2], vv[3]);
            *(float4*)(cp + 4) = make_float4(vv[4], vv[5], vv[6], vv[7]);
        }
    }
}

// ---------------------------------------------------------------------------
// GCN gather: one wave per node. h1[d] = relu(dinv[d]*(Σ_s hW[s]*dinv[s]
//                                        + hW[d]*dinv[d]) + b)
__global__ __launch_bounds__(256)
void gcn_gather(const int* __restrict__ rowptr, const int* __restrict__ csr,
                const float* __restrict__ dinv, const float* __restrict__ hW,
                const float* __restrict__ b, float* __restrict__ h1, int n)
{
    int d = blockIdx.x * 4 + (threadIdx.x >> 6);
    if (d >= n) return;
    int lane = threadIdx.x & 63;
    int r0 = rowptr[d], r1 = rowptr[d + 1];
    float ax = 0.f, ay = 0.f;
    for (int j = r0; j < r1; ++j) {
        int s = csr[j];
        float ds = dinv[s];
        float2 v = ((const float2*)(hW + (size_t)s * 128))[lane];
        ax = fmaf(v.x, ds, ax);
        ay = fmaf(v.y, ds, ay);
    }
    float dd = dinv[d];
    float2 vd = ((const float2*)(hW + (size_t)d * 128))[lane];
    float2 bb = ((const float2*)b)[lane];
    float o0 = fmaxf(fmaf(ax + vd.x * dd, dd, bb.x), 0.f);
    float o1 = fmaxf(fmaf(ay + vd.y * dd, dd, bb.y), 0.f);
    ((float2*)(h1 + (size_t)d * 128))[lane] = make_float2(o0, o1);
}

// SAGE gather: mean[d] = (Σ_s h1[s]) * icnt[d]
__global__ __launch_bounds__(256)
void sage_gather(const int* __restrict__ rowptr, const int* __restrict__ csr,
                 const float* __restrict__ icnt, const float* __restrict__ h1,
                 float* __restrict__ mean, int n)
{
    int d = blockIdx.x * 4 + (threadIdx.x >> 6);
    if (d >= n) return;
    int lane = threadIdx.x & 63;
    int r0 = rowptr[d], r1 = rowptr[d + 1];
    float ax = 0.f, ay = 0.f;
    for (int j = r0; j < r1; ++j) {
        int s = csr[j];
        float2 v = ((const float2*)(h1 + (size_t)s * 128))[lane];
        ax += v.x; ay += v.y;
    }
    float ic = icnt[d];
    ((float2*)(mean + (size_t)d * 128))[lane] = make_float2(ax * ic, ay * ic);
}

// ---------------------------------------------------------------------------
// per-node attention logits: a_s[i][h] = <xW[i,h,:], att_src[h,:]>, same dst
__global__ __launch_bounds__(256)
void att_node(const float* __restrict__ xW, const float* __restrict__ att_src,
              const float* __restrict__ att_dst, float* __restrict__ a_s,
              float* __restrict__ a_d, int n)
{
    int i = blockIdx.x * 4 + (threadIdx.x >> 6);
    if (i >= n) return;
    int lane = threadIdx.x & 63;
#pragma unroll
    for (int h = 0; h < 2; ++h) {
        float2 v  = ((const float2*)(xW + (size_t)i * 256 + h * 128))[lane];
        float2 s2 = ((const float2*)(att_src + h * 128))[lane];
        float2 d2 = ((const float2*)(att_dst + h * 128))[lane];
        float ps = v.x * s2.x + v.y * s2.y;
        float pd = v.x * d2.x + v.y * d2.y;
#pragma unroll
        for (int m = 32; m > 0; m >>= 1) {
            ps += __shfl_xor(ps, m, 64);
            pd += __shfl_xor(pd, m, 64);
        }
        if (lane == 0) { a_s[i * 2 + h] = ps; a_d[i * 2 + h] = pd; }
    }
}

// GAT fused: softmax over incoming edges (+self loop) and weighted gather.
// One wave per node. Lanes 0..31 handle head0 cols lane*4.., 32..63 head1.
__global__ __launch_bounds__(256)
void gat_gather(const int* __restrict__ rowptr, const int* __restrict__ csr,
                const float* __restrict__ a_s, const float* __restrict__ a_d,
                const float* __restrict__ xW, const float* __restrict__ b_gat,
                float* __restrict__ h3, int n)
{
    int d = blockIdx.x * 4 + (threadIdx.x >> 6);
    if (d >= n) return;
    int lane = threadIdx.x & 63;
    int r0 = rowptr[d], r1 = rowptr[d + 1];
    float ad0 = a_d[d * 2], ad1 = a_d[d * 2 + 1];
    float self0 = leaky02(a_s[d * 2] + ad0);
    float self1 = leaky02(a_s[d * 2 + 1] + ad1);

    // pass 1: segment max (edges lane-parallel; self included)
    float m0 = self0, m1 = self1;
    for (int j = r0 + lane; j < r1; j += 64) {
        int s = csr[j];
        m0 = fmaxf(m0, leaky02(a_s[s * 2] + ad0));
        m1 = fmaxf(m1, leaky02(a_s[s * 2 + 1] + ad1));
    }
#pragma unroll
    for (int sh = 32; sh > 0; sh >>= 1) {
        m0 = fmaxf(m0, __shfl_xor(m0, sh, 64));
        m1 = fmaxf(m1, __shfl_xor(m1, sh, 64));
    }
    // pass 2a: exp-sums
    float s0 = 0.f, s1 = 0.f;
    for (int j = r0 + lane; j < r1; j += 64) {
        int s = csr[j];
        s0 += __expf(leaky02(a_s[s * 2] + ad0) - m0);
        s1 += __expf(leaky02(a_s[s * 2 + 1] + ad1) - m1);
    }
#pragma unroll
    for (int sh = 32; sh > 0; sh >>= 1) {
        s0 += __shfl_xor(s0, sh, 64);
        s1 += __shfl_xor(s1, sh, 64);
    }
    s0 += __expf(self0 - m0);
    s1 += __expf(self1 - m1);
    float i0 = 1.f / (s0 + 1e-16f);
    float i1 = 1.f / (s1 + 1e-16f);

    // pass 2b: weighted gather; lane's head
    const bool hi = lane >= 32;
    const float m   = hi ? m1 : m0;
    const float inv = hi ? i1 : i0;
    const float adh = hi ? ad1 : ad0;
    const int   hoff = hi ? 1 : 0;
    float4 acc = make_float4(0.f, 0.f, 0.f, 0.f);
    for (int j = r0; j < r1; ++j) {
        int s = csr[j];
        float w = __expf(leaky02(a_s[s * 2 + hoff] + adh) - m) * inv;
        float4 v = ((const float4*)(xW + (size_t)s * 256))[lane];
        acc.x = fmaf(v.x, w, acc.x);
        acc.y = fmaf(v.y, w, acc.y);
        acc.z = fmaf(v.z, w, acc.z);
        acc.w = fmaf(v.w, w, acc.w);
    }
    // self loop term
    {
        float w = __expf((hi ? self1 : self0) - m) * inv;
        float4 v = ((const float4*)(xW + (size_t)d * 256))[lane];
        acc.x = fmaf(v.x, w, acc.x);
        acc.y = fmaf(v.y, w, acc.y);
        acc.z = fmaf(v.z, w, acc.z);
        acc.w = fmaf(v.w, w, acc.w);
    }
    // mean over heads: combine lane l with lane l^32, write cols l*4..l*4+3
    float c0 = acc.x + __shfl_xor(acc.x, 32, 64);
    float c1 = acc.y + __shfl_xor(acc.y, 32, 64);
    float c2 = acc.z + __shfl_xor(acc.z, 32, 64);
    float c3 = acc.w + __shfl_xor(acc.w, 32, 64);
    if (lane < 32) {
        float4 bb = ((const float4*)b_gat)[lane];
        float4 o;
        o.x = fmaxf(0.5f * c0 + bb.x, 0.f);
        o.y = fmaxf(0.5f * c1 + bb.y, 0.f);
        o.z = fmaxf(0.5f * c2 + bb.z, 0.f);
        o.w = fmaxf(0.5f * c3 + bb.w, 0.f);
        ((float4*)(h3 + (size_t)d * 128))[lane] = o;
    }
}

// final: out[N x 64] = h3 @ W_out + b_out, one wave per row
__global__ __launch_bounds__(256)
void out_gemm(const float* __restrict__ h3, const float* __restrict__ W,
              const float* __restrict__ b, float* __restrict__ out, int n)
{
    int r = blockIdx.x * 4 + (threadIdx.x >> 6);
    if (r >= n) return;
    int lane = threadIdx.x & 63;
    float acc = b[lane];
    const float* hp = h3 + (size_t)r * 128;
#pragma unroll 8
    for (int k = 0; k < 128; ++k)
        acc = fmaf(hp[k], W[k * 64 + lane], acc);
    out[(size_t)r * 64 + lane] = acc;
}

// ---------------------------------------------------------------------------
extern "C" void kernel_launch(void* const* d_in, const int* in_sizes, int n_in,
                              void* d_out, int out_size, void* d_ws, size_t ws_size,
                              hipStream_t stream)
{
    const float* x      = (const float*)d_in[0];
    const int*   ei     = (const int*)d_in[1];
    const int*   nidx   = (const int*)d_in[2];
    const float* emb    = (const float*)d_in[3];
    const float* W_gcn  = (const float*)d_in[4];
    const float* b_gcn  = (const float*)d_in[5];
    const float* W_sl   = (const float*)d_in[6];
    const float* W_sr   = (const float*)d_in[7];
    const float* b_sage = (const float*)d_in[8];
    const float* W_gat  = (const float*)d_in[9];
    const float* att_s  = (const float*)d_in[10];
    const float* att_d  = (const float*)d_in[11];
    const float* b_gat  = (const float*)d_in[12];
    const float* W_out  = (const float*)d_in[13];
    const float* b_out  = (const float*)d_in[14];
    float* out = (float*)d_out;

    const int n = in_sizes[0] / 128;
    const int E = in_sizes[1] / 2;
    const int* esrc = ei;
    const int* edst = ei + E;

    const size_t P = (size_t)n * 128;
    float* ws   = (float*)d_ws;
    float* bufA = ws;                 // hW -> mean -> h3
    float* h1   = ws + P;
    float* h2   = ws + 2 * P;
    float* xW   = ws + 3 * P;         // 2P
    float* deg  = ws + 5 * P;         // n
    float* dinv = deg + n;            // n
    float* icnt = dinv + n;           // n
    float* a_s  = icnt + n;           // 2n
    float* a_d  = a_s + 2 * n;        // 2n
    int* rowptr = (int*)(a_d + 2 * n);// n+1
    int* fill   = rowptr + n + 1;     // n
    int* csr    = fill + n;           // E

    const int TB = 256;
    int nblk_n     = (n + TB - 1) / TB;
    int nblk_e     = (E + TB - 1) / TB;
    int nblk_wav_n = (n + 3) / 4;
    int gemm_rows  = (n + 63) / 64;

    // --- degrees + CSR build ---
    fill_f32<<<nblk_n, TB, 0, stream>>>(deg, 1.0f, n);
    deg_edges<<<nblk_e, TB, 0, stream>>>(edst, deg, E);
    norm_node<<<nblk_n, TB, 0, stream>>>(deg, dinv, icnt, n);
    scan_rowptr<<<1, 1024, 0, stream>>>(deg, rowptr, n);
    hipMemsetAsync(fill, 0, (size_t)n * sizeof(int), stream);
    csr_fill<<<nblk_e, TB, 0, stream>>>(esrc, edst, rowptr, fill, csr, E);

    // --- GCN ---
    gemm_k128<true, false, false, true><<<dim3(gemm_rows, 1), TB, 0, stream>>>(
        x, W_gcn, emb, W_gcn + 128 * 128, nidx, nullptr, bufA, n, 128, 128);
    gcn_gather<<<nblk_wav_n, TB, 0, stream>>>(rowptr, csr, dinv, bufA, b_gcn, h1, n);

    // --- SAGE ---
    sage_gather<<<nblk_wav_n, TB, 0, stream>>>(rowptr, csr, icnt, h1, bufA, n);
    gemm_k128<true, true, true, false><<<dim3(gemm_rows, 1), TB, 0, stream>>>(
        bufA, W_sl, h1, W_sr, nullptr, b_sage, h2, n, 128, 128);

    // --- GAT ---
    gemm_k128<false, false, false, false><<<dim3(gemm_rows, 2), TB, 0, stream>>>(
        h2, W_gat, nullptr, nullptr, nullptr, nullptr, xW, n, 256, 256);
    att_node<<<nblk_wav_n, TB, 0, stream>>>(xW, att_s, att_d, a_s, a_d, n);
    gat_gather<<<nblk_wav_n, TB, 0, stream>>>(rowptr, csr, a_s, a_d, xW, b_gat, bufA, n);

    // --- output ---
    out_gemm<<<nblk_wav_n, TB, 0, stream>>>(bufA, W_out, b_out, out, n);
}

// Round 3
// 900.054 us; speedup vs baseline: 9.7496x; 1.3704x over previous
//
#include <hip/hip_runtime.h>

// ---------------------------------------------------------------------------
// StructuralGNN: GCN -> SAGE -> GAT(2 heads) -> Linear on N=50k, E=1.6M, D=128
// Round 3: unrolled gathers (4 rows in flight), 2-level scan, 128x128 fp32
// GEMM tiles, att-logits fused into GAT GEMM epilogue, out-GEMM fused into
// gat_gather.
// ---------------------------------------------------------------------------

static __device__ __forceinline__ float leaky02(float x) {
    return x > 0.f ? x : 0.2f * x;
}
static __device__ __forceinline__ void atomAddF(float* p, float v) {
    unsafeAtomicAdd(p, v);   // native global_atomic_add_f32 on gfx950
}

// ---------------------------------------------------------------------------
__global__ void fill_f32(float* __restrict__ p, float v, int n) {
    int i = blockIdx.x * blockDim.x + threadIdx.x;
    if (i < n) p[i] = v;
}

__global__ void deg_edges(const int* __restrict__ dst, float* __restrict__ deg, int E) {
    int e = blockIdx.x * blockDim.x + threadIdx.x;
    if (e < E) atomAddF(&deg[dst[e]], 1.0f);
}

__global__ void norm_node(const float* __restrict__ deg, float* __restrict__ dinv,
                          float* __restrict__ icnt, int n) {
    int i = blockIdx.x * blockDim.x + threadIdx.x;
    if (i < n) {
        float d = deg[i];                 // >= 1 (self loop)
        dinv[i] = rsqrtf(d);
        icnt[i] = 1.0f / fmaxf(d - 1.0f, 1.0f);   // SAGE cnt = deg - 1
    }
}

// --------------------- two-level exclusive scan ----------------------------
// phase 1: per-1024-chunk sums
__global__ __launch_bounds__(256)
void scan_part(const float* __restrict__ deg, int* __restrict__ partial, int n)
{
    int t = threadIdx.x;
    int base = blockIdx.x * 1024 + t * 4;
    int s = 0;
#pragma unroll
    for (int i = 0; i < 4; ++i) {
        int g = base + i;
        if (g < n) s += (int)deg[g] - 1;
    }
#pragma unroll
    for (int m = 32; m > 0; m >>= 1) s += __shfl_xor(s, m, 64);
    __shared__ int wsum[4];
    if ((t & 63) == 0) wsum[t >> 6] = s;
    __syncthreads();
    if (t == 0) partial[blockIdx.x] = wsum[0] + wsum[1] + wsum[2] + wsum[3];
}

// phase 2: single wave scans chunk sums -> exclusive offsets (any nb)
__global__ __launch_bounds__(64)
void scan_offsets(int* __restrict__ partial, int nb)
{
    int t = threadIdx.x;
    int carry = 0;
    for (int base = 0; base < nb; base += 64) {
        int i = base + t;
        int v = (i < nb) ? partial[i] : 0;
        int incl = v;
#pragma unroll
        for (int m = 1; m < 64; m <<= 1) {
            int o = __shfl_up(incl, m, 64);
            if (t >= m) incl += o;
        }
        if (i < nb) partial[i] = incl - v + carry;
        carry += __shfl(incl, 63, 64);
    }
}

// phase 3: per-chunk exclusive scan + offset -> rowptr
__global__ __launch_bounds__(256)
void scan_write(const float* __restrict__ deg, const int* __restrict__ partial,
                int* __restrict__ rowptr, int n)
{
    __shared__ int tmp[256];
    int t = threadIdx.x;
    int base = blockIdx.x * 1024 + t * 4;
    int v[4]; int s = 0;
#pragma unroll
    for (int i = 0; i < 4; ++i) {
        int g = base + i;
        v[i] = (g < n) ? ((int)deg[g] - 1) : 0;
        s += v[i];
    }
    tmp[t] = s;
    __syncthreads();
    for (int off = 1; off < 256; off <<= 1) {
        int a = (t >= off) ? tmp[t - off] : 0;
        __syncthreads();
        tmp[t] += a;
        __syncthreads();
    }
    int run = tmp[t] - s + partial[blockIdx.x];
#pragma unroll
    for (int i = 0; i < 4; ++i) {
        int g = base + i;
        run += v[i];
        if (g < n) rowptr[g + 1] = run;
    }
    if (blockIdx.x == 0 && t == 0) rowptr[0] = 0;
}

__global__ void csr_fill(const int* __restrict__ src, const int* __restrict__ dst,
                         const int* __restrict__ rowptr, int* __restrict__ fill,
                         int* __restrict__ csr, int E)
{
    int e = blockIdx.x * blockDim.x + threadIdx.x;
    if (e >= E) return;
    int d = dst[e];
    int pos = rowptr[d] + atomicAdd(&fill[d], 1);
    csr[pos] = src[e];
}

// ---------------------------------------------------------------------------
// C[128-row tile x 128-col slice] = act( scale*(A1@W1 + A2[idx]@W2) + bias )
// 256 threads, 8x8 micro-tile. Optional fused attention-logit epilogue.
template<bool HAS_A2, bool RELU, bool HAS_BIAS, bool HAS_IDX, bool SCALE, bool ATT>
__global__ __launch_bounds__(256)
void gemm_k128(const float* __restrict__ A1, const float* __restrict__ W1,
               const float* __restrict__ A2, const float* __restrict__ W2,
               const int* __restrict__ idx2, const float* __restrict__ bias,
               const float* __restrict__ scale,
               const float* __restrict__ att_src, const float* __restrict__ att_dst,
               float* __restrict__ a_s, float* __restrict__ a_d,
               float* __restrict__ C, int nrows, int ncW, int ncC)
{
    __shared__ float As[128][33];
    __shared__ float Ws[32][128];
    const int t = threadIdx.x;
    const int tc = t & 15;        // 16 col groups * 8 cols
    const int tr = t >> 4;        // 16 row groups * 8 rows
    const int row0 = blockIdx.x * 128;
    const int colOff = blockIdx.y * 128;

    float acc[8][8] = {};

    const int npass = HAS_A2 ? 2 : 1;
    for (int p = 0; p < npass; ++p) {
        const float* A = (p == 0) ? A1 : A2;
        const float* W = (p == 0) ? W1 : W2;
        for (int kt = 0; kt < 4; ++kt) {
#pragma unroll
            for (int i = 0; i < 4; ++i) {       // stage A: 128 x 32
                int f = i * 256 + t;
                int r = f >> 3, c4 = (f & 7) << 2;
                int row = row0 + r; if (row >= nrows) row = nrows - 1;
                int arow = (p == 1 && HAS_IDX) ? idx2[row] : row;
                float4 v = *(const float4*)(A + (size_t)arow * 128 + kt * 32 + c4);
                As[r][c4 + 0] = v.x; As[r][c4 + 1] = v.y;
                As[r][c4 + 2] = v.z; As[r][c4 + 3] = v.w;
            }
#pragma unroll
            for (int i = 0; i < 4; ++i) {       // stage W: 32 x 128
                int f = i * 256 + t;
                int wr = f >> 5, wc4 = (f & 31) << 2;
                *(float4*)&Ws[wr][wc4] =
                    *(const float4*)(W + (size_t)(kt * 32 + wr) * ncW + colOff + wc4);
            }
            __syncthreads();
#pragma unroll
            for (int kk = 0; kk < 32; ++kk) {
                float a[8], w[8];
#pragma unroll
                for (int i = 0; i < 8; ++i) a[i] = As[tr * 8 + i][kk];
#pragma unroll
                for (int j = 0; j < 8; ++j) w[j] = Ws[kk][tc * 8 + j];
#pragma unroll
                for (int i = 0; i < 8; ++i)
#pragma unroll
                    for (int j = 0; j < 8; ++j)
                        acc[i][j] = fmaf(a[i], w[j], acc[i][j]);
            }
            __syncthreads();
        }
    }

    float as_v[8], ad_v[8];
    if (ATT) {
#pragma unroll
        for (int j = 0; j < 8; ++j) {
            as_v[j] = att_src[colOff + tc * 8 + j];
            ad_v[j] = att_dst[colOff + tc * 8 + j];
        }
    }
#pragma unroll
    for (int i = 0; i < 8; ++i) {
        int row = row0 + tr * 8 + i;
        bool ok = row < nrows;
        float sc = 1.f;
        if (SCALE) sc = ok ? scale[row] : 0.f;
        float vv[8];
#pragma unroll
        for (int j = 0; j < 8; ++j) {
            float v = acc[i][j];
            if (SCALE) v *= sc;
            if (HAS_BIAS) v += bias[colOff + tc * 8 + j];
            if (RELU) v = fmaxf(v, 0.f);
            vv[j] = v;
        }
        if (ok) {
            float* cp = C + (size_t)row * ncC + colOff + tc * 8;
            *(float4*)cp = make_float4(vv[0], vv[1], vv[2], vv[3]);
            *(float4*)(cp + 4) = make_float4(vv[4], vv[5], vv[6], vv[7]);
        }
        if (ATT) {
            float ps = 0.f, pd = 0.f;
#pragma unroll
            for (int j = 0; j < 8; ++j) {
                ps = fmaf(vv[j], as_v[j], ps);
                pd = fmaf(vv[j], ad_v[j], pd);
            }
#pragma unroll
            for (int m = 1; m < 16; m <<= 1) {
                ps += __shfl_xor(ps, m, 64);
                pd += __shfl_xor(pd, m, 64);
            }
            if (ok && tc == 0) {
                a_s[row * 2 + blockIdx.y] = ps;
                a_d[row * 2 + blockIdx.y] = pd;
            }
        }
    }
}

// ---------------------------------------------------------------------------
// GCN gather (hWs pre-scaled by dinv[src]):
// h1[d] = relu(dinv[d]*(Σ_s hWs[s] + hWs[d]) + b)
__global__ __launch_bounds__(256)
void gcn_gather(const int* __restrict__ rowptr, const int* __restrict__ csr,
                const float* __restrict__ dinv, const float* __restrict__ hWs,
                const float* __restrict__ b, float* __restrict__ h1, int n)
{
    int d = blockIdx.x * 4 + (threadIdx.x >> 6);
    if (d >= n) return;
    int lane = threadIdx.x & 63;
    int r0 = rowptr[d], r1 = rowptr[d + 1];
    float ax = 0.f, ay = 0.f;
    int j = r0;
    for (; j + 4 <= r1; j += 4) {
        int s0 = csr[j], s1 = csr[j + 1], s2 = csr[j + 2], s3 = csr[j + 3];
        float2 v0 = ((const float2*)(hWs + (size_t)s0 * 128))[lane];
        float2 v1 = ((const float2*)(hWs + (size_t)s1 * 128))[lane];
        float2 v2 = ((const float2*)(hWs + (size_t)s2 * 128))[lane];
        float2 v3 = ((const float2*)(hWs + (size_t)s3 * 128))[lane];
        ax += (v0.x + v1.x) + (v2.x + v3.x);
        ay += (v0.y + v1.y) + (v2.y + v3.y);
    }
    for (; j < r1; ++j) {
        int s = csr[j];
        float2 v = ((const float2*)(hWs + (size_t)s * 128))[lane];
        ax += v.x; ay += v.y;
    }
    float dd = dinv[d];
    float2 vd = ((const float2*)(hWs + (size_t)d * 128))[lane];
    float2 bb = ((const float2*)b)[lane];
    float o0 = fmaxf(fmaf(ax + vd.x, dd, bb.x), 0.f);
    float o1 = fmaxf(fmaf(ay + vd.y, dd, bb.y), 0.f);
    ((float2*)(h1 + (size_t)d * 128))[lane] = make_float2(o0, o1);
}

// SAGE gather: mean[d] = (Σ_s h1[s]) * icnt[d]
__global__ __launch_bounds__(256)
void sage_gather(const int* __restrict__ rowptr, const int* __restrict__ csr,
                 const float* __restrict__ icnt, const float* __restrict__ h1,
                 float* __restrict__ mean, int n)
{
    int d = blockIdx.x * 4 + (threadIdx.x >> 6);
    if (d >= n) return;
    int lane = threadIdx.x & 63;
    int r0 = rowptr[d], r1 = rowptr[d + 1];
    float ax = 0.f, ay = 0.f;
    int j = r0;
    for (; j + 4 <= r1; j += 4) {
        int s0 = csr[j], s1 = csr[j + 1], s2 = csr[j + 2], s3 = csr[j + 3];
        float2 v0 = ((const float2*)(h1 + (size_t)s0 * 128))[lane];
        float2 v1 = ((const float2*)(h1 + (size_t)s1 * 128))[lane];
        float2 v2 = ((const float2*)(h1 + (size_t)s2 * 128))[lane];
        float2 v3 = ((const float2*)(h1 + (size_t)s3 * 128))[lane];
        ax += (v0.x + v1.x) + (v2.x + v3.x);
        ay += (v0.y + v1.y) + (v2.y + v3.y);
    }
    for (; j < r1; ++j) {
        int s = csr[j];
        float2 v = ((const float2*)(h1 + (size_t)s * 128))[lane];
        ax += v.x; ay += v.y;
    }
    float ic = icnt[d];
    ((float2*)(mean + (size_t)d * 128))[lane] = make_float2(ax * ic, ay * ic);
}

// ---------------------------------------------------------------------------
// GAT fused: softmax over incoming edges (+self), weighted gather, head-mean,
// bias+relu, and final out = h3 @ W_out + b_out. One wave per node.
__global__ __launch_bounds__(256)
void gat_gather(const int* __restrict__ rowptr, const int* __restrict__ csr,
                const float* __restrict__ a_s, const float* __restrict__ a_d,
                const float* __restrict__ xW, const float* __restrict__ b_gat,
                const float* __restrict__ W_out, const float* __restrict__ b_out,
                float* __restrict__ out, int n)
{
    __shared__ float h3row[4][128];
    int wv = threadIdx.x >> 6;
    int d = blockIdx.x * 4 + wv;
    if (d >= n) return;
    int lane = threadIdx.x & 63;
    int r0 = rowptr[d], r1 = rowptr[d + 1];
    float ad0 = a_d[d * 2], ad1 = a_d[d * 2 + 1];
    float self0 = leaky02(a_s[d * 2] + ad0);
    float self1 = leaky02(a_s[d * 2 + 1] + ad1);

    // pass 1: segment max (lane-parallel)
    float m0 = self0, m1 = self1;
    for (int j = r0 + lane; j < r1; j += 64) {
        int s = csr[j];
        m0 = fmaxf(m0, leaky02(a_s[s * 2] + ad0));
        m1 = fmaxf(m1, leaky02(a_s[s * 2 + 1] + ad1));
    }
#pragma unroll
    for (int sh = 32; sh > 0; sh >>= 1) {
        m0 = fmaxf(m0, __shfl_xor(m0, sh, 64));
        m1 = fmaxf(m1, __shfl_xor(m1, sh, 64));
    }
    // pass 2a: exp-sums (lane-parallel)
    float s0 = 0.f, s1 = 0.f;
    for (int j = r0 + lane; j < r1; j += 64) {
        int s = csr[j];
        s0 += __expf(leaky02(a_s[s * 2] + ad0) - m0);
        s1 += __expf(leaky02(a_s[s * 2 + 1] + ad1) - m1);
    }
#pragma unroll
    for (int sh = 32; sh > 0; sh >>= 1) {
        s0 += __shfl_xor(s0, sh, 64);
        s1 += __shfl_xor(s1, sh, 64);
    }
    s0 += __expf(self0 - m0);
    s1 += __expf(self1 - m1);
    float i0 = 1.f / (s0 + 1e-16f);
    float i1 = 1.f / (s1 + 1e-16f);

    // pass 2b: weighted gather, 4 edges in flight
    const bool hi = lane >= 32;
    const float m   = hi ? m1 : m0;
    const float inv = hi ? i1 : i0;
    const float adh = hi ? ad1 : ad0;
    const int   hoff = hi ? 1 : 0;
    float4 acc = make_float4(0.f, 0.f, 0.f, 0.f);
    int j = r0;
    for (; j + 4 <= r1; j += 4) {
        int e0 = csr[j], e1 = csr[j + 1], e2 = csr[j + 2], e3 = csr[j + 3];
        float av0 = a_s[e0 * 2 + hoff], av1 = a_s[e1 * 2 + hoff];
        float av2 = a_s[e2 * 2 + hoff], av3 = a_s[e3 * 2 + hoff];
        float4 v0 = ((const float4*)(xW + (size_t)e0 * 256))[lane];
        float4 v1 = ((const float4*)(xW + (size_t)e1 * 256))[lane];
        float4 v2 = ((const float4*)(xW + (size_t)e2 * 256))[lane];
        float4 v3 = ((const float4*)(xW + (size_t)e3 * 256))[lane];
        float w0 = __expf(leaky02(av0 + adh) - m) * inv;
        float w1 = __expf(leaky02(av1 + adh) - m) * inv;
        float w2 = __expf(leaky02(av2 + adh) - m) * inv;
        float w3 = __expf(leaky02(av3 + adh) - m) * inv;
        acc.x = fmaf(v0.x, w0, fmaf(v1.x, w1, fmaf(v2.x, w2, fmaf(v3.x, w3, acc.x))));
        acc.y = fmaf(v0.y, w0, fmaf(v1.y, w1, fmaf(v2.y, w2, fmaf(v3.y, w3, acc.y))));
        acc.z = fmaf(v0.z, w0, fmaf(v1.z, w1, fmaf(v2.z, w2, fmaf(v3.z, w3, acc.z))));
        acc.w = fmaf(v0.w, w0, fmaf(v1.w, w1, fmaf(v2.w, w2, fmaf(v3.w, w3, acc.w))));
    }
    for (; j < r1; ++j) {
        int s = csr[j];
        float w = __expf(leaky02(a_s[s * 2 + hoff] + adh) - m) * inv;
        float4 v = ((const float4*)(xW + (size_t)s * 256))[lane];
        acc.x = fmaf(v.x, w, acc.x);
        acc.y = fmaf(v.y, w, acc.y);
        acc.z = fmaf(v.z, w, acc.z);
        acc.w = fmaf(v.w, w, acc.w);
    }
    { // self loop
        float w = __expf((hi ? self1 : self0) - m) * inv;
        float4 v = ((const float4*)(xW + (size_t)d * 256))[lane];
        acc.x = fmaf(v.x, w, acc.x);
        acc.y = fmaf(v.y, w, acc.y);
        acc.z = fmaf(v.z, w, acc.z);
        acc.w = fmaf(v.w, w, acc.w);
    }
    // head-mean + bias + relu -> h3 row in LDS
    float c0 = acc.x + __shfl_xor(acc.x, 32, 64);
    float c1 = acc.y + __shfl_xor(acc.y, 32, 64);
    float c2 = acc.z + __shfl_xor(acc.z, 32, 64);
    float c3 = acc.w + __shfl_xor(acc.w, 32, 64);
    if (lane < 32) {
        float4 bb = ((const float4*)b_gat)[lane];
        float4 o;
        o.x = fmaxf(0.5f * c0 + bb.x, 0.f);
        o.y = fmaxf(0.5f * c1 + bb.y, 0.f);
        o.z = fmaxf(0.5f * c2 + bb.z, 0.f);
        o.w = fmaxf(0.5f * c3 + bb.w, 0.f);
        ((float4*)h3row[wv])[lane] = o;
    }
    __threadfence_block();   // LDS write visibility within the wave
    // fused out layer: out[d, lane] = <h3row, W_out[:,lane]> + b_out[lane]
    const float* hr = h3row[wv];
    float t0 = 0.f, t1 = 0.f, t2 = 0.f, t3 = 0.f;
#pragma unroll 8
    for (int k = 0; k < 128; k += 4) {
        t0 = fmaf(hr[k + 0], W_out[(k + 0) * 64 + lane], t0);
        t1 = fmaf(hr[k + 1], W_out[(k + 1) * 64 + lane], t1);
        t2 = fmaf(hr[k + 2], W_out[(k + 2) * 64 + lane], t2);
        t3 = fmaf(hr[k + 3], W_out[(k + 3) * 64 + lane], t3);
    }
    out[(size_t)d * 64 + lane] = (t0 + t1) + (t2 + t3) + b_out[lane];
}

// ---------------------------------------------------------------------------
extern "C" void kernel_launch(void* const* d_in, const int* in_sizes, int n_in,
                              void* d_out, int out_size, void* d_ws, size_t ws_size,
                              hipStream_t stream)
{
    const float* x      = (const float*)d_in[0];
    const int*   ei     = (const int*)d_in[1];
    const int*   nidx   = (const int*)d_in[2];
    const float* emb    = (const float*)d_in[3];
    const float* W_gcn  = (const float*)d_in[4];
    const float* b_gcn  = (const float*)d_in[5];
    const float* W_sl   = (const float*)d_in[6];
    const float* W_sr   = (const float*)d_in[7];
    const float* b_sage = (const float*)d_in[8];
    const float* W_gat  = (const float*)d_in[9];
    const float* att_s  = (const float*)d_in[10];
    const float* att_d  = (const float*)d_in[11];
    const float* b_gat  = (const float*)d_in[12];
    const float* W_out  = (const float*)d_in[13];
    const float* b_out  = (const float*)d_in[14];
    float* out = (float*)d_out;

    const int n = in_sizes[0] / 128;
    const int E = in_sizes[1] / 2;
    const int* esrc = ei;
    const int* edst = ei + E;

    const size_t P = (size_t)n * 128;
    float* ws   = (float*)d_ws;
    float* bufA = ws;                 // hWs -> mean
    float* h1   = ws + P;
    float* h2   = ws + 2 * P;
    float* xW   = ws + 3 * P;         // 2P
    float* deg  = ws + 5 * P;         // n
    float* dinv = deg + n;            // n
    float* icnt = dinv + n;           // n
    float* a_s  = icnt + n;           // 2n
    float* a_d  = a_s + 2 * n;        // 2n
    int* rowptr = (int*)(a_d + 2 * n);// n+1
    int* fill   = rowptr + n + 1;     // n
    int* partial= fill + n;           // ceil(n/1024)
    int* csr    = partial + ((n + 1023) / 1024) + 1;  // E

    const int TB = 256;
    int nblk_n     = (n + TB - 1) / TB;
    int nblk_e     = (E + TB - 1) / TB;
    int nblk_wav_n = (n + 3) / 4;
    int gemm_rows  = (n + 127) / 128;
    int nb_scan    = (n + 1023) / 1024;

    // --- degrees + CSR build ---
    fill_f32<<<nblk_n, TB, 0, stream>>>(deg, 1.0f, n);
    deg_edges<<<nblk_e, TB, 0, stream>>>(edst, deg, E);
    norm_node<<<nblk_n, TB, 0, stream>>>(deg, dinv, icnt, n);
    scan_part<<<nb_scan, TB, 0, stream>>>(deg, partial, n);
    scan_offsets<<<1, 64, 0, stream>>>(partial, nb_scan);
    scan_write<<<nb_scan, TB, 0, stream>>>(deg, partial, rowptr, n);
    hipMemsetAsync(fill, 0, (size_t)n * sizeof(int), stream);
    csr_fill<<<nblk_e, TB, 0, stream>>>(esrc, edst, rowptr, fill, csr, E);

    // --- GCN: hWs = (x@Wg_top + emb@Wg_bot) * dinv[row] ---
    gemm_k128<true, false, false, true, true, false><<<dim3(gemm_rows, 1), TB, 0, stream>>>(
        x, W_gcn, emb, W_gcn + 128 * 128, nidx, nullptr, dinv,
        nullptr, nullptr, nullptr, nullptr, bufA, n, 128, 128);
    gcn_gather<<<nblk_wav_n, TB, 0, stream>>>(rowptr, csr, dinv, bufA, b_gcn, h1, n);

    // --- SAGE ---
    sage_gather<<<nblk_wav_n, TB, 0, stream>>>(rowptr, csr, icnt, h1, bufA, n);
    gemm_k128<true, true, true, false, false, false><<<dim3(gemm_rows, 1), TB, 0, stream>>>(
        bufA, W_sl, h1, W_sr, nullptr, b_sage, nullptr,
        nullptr, nullptr, nullptr, nullptr, h2, n, 128, 128);

    // --- GAT: xW + fused attention logits ---
    gemm_k128<false, false, false, false, false, true><<<dim3(gemm_rows, 2), TB, 0, stream>>>(
        h2, W_gat, nullptr, nullptr, nullptr, nullptr, nullptr,
        att_s, att_d, a_s, a_d, xW, n, 256, 256);
    gat_gather<<<nblk_wav_n, TB, 0, stream>>>(rowptr, csr, a_s, a_d, xW, b_gat,
                                              W_out, b_out, out, n);
}

// Round 4
// 865.854 us; speedup vs baseline: 10.1347x; 1.0395x over previous
//
#include <hip/hip_runtime.h>

// ---------------------------------------------------------------------------
// StructuralGNN: GCN -> SAGE -> GAT(2 heads) -> Linear on N=50k, E=1.6M, D=128
// Round 4: single-pass GAT softmax-gather (no segment-max pass: logits are
// O(1), exp is safe and max-shift cancels algebraically), float4 paired-edge
// gcn/sage gathers, fused norm into scan, int degrees.
// ---------------------------------------------------------------------------

static __device__ __forceinline__ float leaky02(float x) {
    return x > 0.f ? x : 0.2f * x;
}

// ---------------------------------------------------------------------------
__global__ void deg_edges(const int* __restrict__ dst, int* __restrict__ degi, int E) {
    int e = blockIdx.x * blockDim.x + threadIdx.x;
    if (e < E) atomicAdd(&degi[dst[e]], 1);
}

// per-1024-chunk sums of edge counts + dinv/icnt computation
__global__ __launch_bounds__(256)
void scan_part_norm(const int* __restrict__ degi, int* __restrict__ partial,
                    float* __restrict__ dinv, float* __restrict__ icnt, int n)
{
    int t = threadIdx.x;
    int base = blockIdx.x * 1024 + t * 4;
    int s = 0;
#pragma unroll
    for (int i = 0; i < 4; ++i) {
        int g = base + i;
        if (g < n) {
            int de = degi[g];                    // in-edges (no self)
            s += de;
            dinv[g] = rsqrtf((float)(de + 1));   // GCN deg includes self loop
            icnt[g] = 1.0f / (float)(de > 1 ? de : 1);
        }
    }
#pragma unroll
    for (int m = 32; m > 0; m >>= 1) s += __shfl_xor(s, m, 64);
    __shared__ int wsum[4];
    if ((t & 63) == 0) wsum[t >> 6] = s;
    __syncthreads();
    if (t == 0) partial[blockIdx.x] = wsum[0] + wsum[1] + wsum[2] + wsum[3];
}

// single wave scans chunk sums -> exclusive offsets
__global__ __launch_bounds__(64)
void scan_offsets(int* __restrict__ partial, int nb)
{
    int t = threadIdx.x;
    int carry = 0;
    for (int base = 0; base < nb; base += 64) {
        int i = base + t;
        int v = (i < nb) ? partial[i] : 0;
        int incl = v;
#pragma unroll
        for (int m = 1; m < 64; m <<= 1) {
            int o = __shfl_up(incl, m, 64);
            if (t >= m) incl += o;
        }
        if (i < nb) partial[i] = incl - v + carry;
        carry += __shfl(incl, 63, 64);
    }
}

// per-chunk exclusive scan + chunk offset -> rowptr
__global__ __launch_bounds__(256)
void scan_write(const int* __restrict__ degi, const int* __restrict__ partial,
                int* __restrict__ rowptr, int n)
{
    __shared__ int tmp[256];
    int t = threadIdx.x;
    int base = blockIdx.x * 1024 + t * 4;
    int v[4]; int s = 0;
#pragma unroll
    for (int i = 0; i < 4; ++i) {
        int g = base + i;
        v[i] = (g < n) ? degi[g] : 0;
        s += v[i];
    }
    tmp[t] = s;
    __syncthreads();
    for (int off = 1; off < 256; off <<= 1) {
        int a = (t >= off) ? tmp[t - off] : 0;
        __syncthreads();
        tmp[t] += a;
        __syncthreads();
    }
    int run = tmp[t] - s + partial[blockIdx.x];
#pragma unroll
    for (int i = 0; i < 4; ++i) {
        int g = base + i;
        run += v[i];
        if (g < n) rowptr[g + 1] = run;
    }
    if (blockIdx.x == 0 && t == 0) rowptr[0] = 0;
}

__global__ void csr_fill(const int* __restrict__ src, const int* __restrict__ dst,
                         const int* __restrict__ rowptr, int* __restrict__ fill,
                         int* __restrict__ csr, int E)
{
    int e = blockIdx.x * blockDim.x + threadIdx.x;
    if (e >= E) return;
    int d = dst[e];
    int pos = rowptr[d] + atomicAdd(&fill[d], 1);
    csr[pos] = src[e];
}

// ---------------------------------------------------------------------------
// C[128-row tile x 128-col slice] = act( scale*(A1@W1 + A2[idx]@W2) + bias )
// 256 threads, 8x8 micro-tile. Optional fused attention-logit epilogue.
template<bool HAS_A2, bool RELU, bool HAS_BIAS, bool HAS_IDX, bool SCALE, bool ATT>
__global__ __launch_bounds__(256)
void gemm_k128(const float* __restrict__ A1, const float* __restrict__ W1,
               const float* __restrict__ A2, const float* __restrict__ W2,
               const int* __restrict__ idx2, const float* __restrict__ bias,
               const float* __restrict__ scale,
               const float* __restrict__ att_src, const float* __restrict__ att_dst,
               float* __restrict__ a_s, float* __restrict__ a_d,
               float* __restrict__ C, int nrows, int ncW, int ncC)
{
    __shared__ float As[128][33];
    __shared__ float Ws[32][128];
    const int t = threadIdx.x;
    const int tc = t & 15;        // 16 col groups * 8 cols
    const int tr = t >> 4;        // 16 row groups * 8 rows
    const int row0 = blockIdx.x * 128;
    const int colOff = blockIdx.y * 128;

    float acc[8][8] = {};

    const int npass = HAS_A2 ? 2 : 1;
    for (int p = 0; p < npass; ++p) {
        const float* A = (p == 0) ? A1 : A2;
        const float* W = (p == 0) ? W1 : W2;
        for (int kt = 0; kt < 4; ++kt) {
#pragma unroll
            for (int i = 0; i < 4; ++i) {       // stage A: 128 x 32
                int f = i * 256 + t;
                int r = f >> 3, c4 = (f & 7) << 2;
                int row = row0 + r; if (row >= nrows) row = nrows - 1;
                int arow = (p == 1 && HAS_IDX) ? idx2[row] : row;
                float4 v = *(const float4*)(A + (size_t)arow * 128 + kt * 32 + c4);
                As[r][c4 + 0] = v.x; As[r][c4 + 1] = v.y;
                As[r][c4 + 2] = v.z; As[r][c4 + 3] = v.w;
            }
#pragma unroll
            for (int i = 0; i < 4; ++i) {       // stage W: 32 x 128
                int f = i * 256 + t;
                int wr = f >> 5, wc4 = (f & 31) << 2;
                *(float4*)&Ws[wr][wc4] =
                    *(const float4*)(W + (size_t)(kt * 32 + wr) * ncW + colOff + wc4);
            }
            __syncthreads();
#pragma unroll
            for (int kk = 0; kk < 32; ++kk) {
                float a[8], w[8];
#pragma unroll
                for (int i = 0; i < 8; ++i) a[i] = As[tr * 8 + i][kk];
#pragma unroll
                for (int j = 0; j < 8; ++j) w[j] = Ws[kk][tc * 8 + j];
#pragma unroll
                for (int i = 0; i < 8; ++i)
#pragma unroll
                    for (int j = 0; j < 8; ++j)
                        acc[i][j] = fmaf(a[i], w[j], acc[i][j]);
            }
            __syncthreads();
        }
    }

    float as_v[8], ad_v[8];
    if (ATT) {
#pragma unroll
        for (int j = 0; j < 8; ++j) {
            as_v[j] = att_src[colOff + tc * 8 + j];
            ad_v[j] = att_dst[colOff + tc * 8 + j];
        }
    }
#pragma unroll
    for (int i = 0; i < 8; ++i) {
        int row = row0 + tr * 8 + i;
        bool ok = row < nrows;
        float sc = 1.f;
        if (SCALE) sc = ok ? scale[row] : 0.f;
        float vv[8];
#pragma unroll
        for (int j = 0; j < 8; ++j) {
            float v = acc[i][j];
            if (SCALE) v *= sc;
            if (HAS_BIAS) v += bias[colOff + tc * 8 + j];
            if (RELU) v = fmaxf(v, 0.f);
            vv[j] = v;
        }
        if (ok) {
            float* cp = C + (size_t)row * ncC + colOff + tc * 8;
            *(float4*)cp = make_float4(vv[0], vv[1], vv[2], vv[3]);
            *(float4*)(cp + 4) = make_float4(vv[4], vv[5], vv[6], vv[7]);
        }
        if (ATT) {
            float ps = 0.f, pd = 0.f;
#pragma unroll
            for (int j = 0; j < 8; ++j) {
                ps = fmaf(vv[j], as_v[j], ps);
                pd = fmaf(vv[j], ad_v[j], pd);
            }
#pragma unroll
            for (int m = 1; m < 16; m <<= 1) {
                ps += __shfl_xor(ps, m, 64);
                pd += __shfl_xor(pd, m, 64);
            }
            if (ok && tc == 0) {
                a_s[row * 2 + blockIdx.y] = ps;
                a_d[row * 2 + blockIdx.y] = pd;
            }
        }
    }
}

// ---------------------------------------------------------------------------
// GCN gather (hWs pre-scaled by dinv[src]). float4 cols, paired edges:
// lanes 0-31 take even edges, 32-63 odd edges; combine via shfl_xor(32).
// h1[d] = relu(dinv[d]*(Σ_s hWs[s] + hWs[d]) + b)
__global__ __launch_bounds__(256)
void gcn_gather(const int* __restrict__ rowptr, const int* __restrict__ csr,
                const float* __restrict__ dinv, const float* __restrict__ hWs,
                const float* __restrict__ b, float* __restrict__ h1, int n)
{
    int d = blockIdx.x * 4 + (threadIdx.x >> 6);
    if (d >= n) return;
    int lane = threadIdx.x & 63;
    int half = lane >> 5;          // 0: even edges, 1: odd edges
    int c = (lane & 31) << 2;      // column group (float4)
    int r0 = rowptr[d], r1 = rowptr[d + 1];
    float4 acc = make_float4(0.f, 0.f, 0.f, 0.f);
    int j = r0 + half;
    for (; j + 6 < r1; j += 8) {
        int s0 = csr[j], s1 = csr[j + 2], s2 = csr[j + 4], s3 = csr[j + 6];
        float4 v0 = *(const float4*)(hWs + (size_t)s0 * 128 + c);
        float4 v1 = *(const float4*)(hWs + (size_t)s1 * 128 + c);
        float4 v2 = *(const float4*)(hWs + (size_t)s2 * 128 + c);
        float4 v3 = *(const float4*)(hWs + (size_t)s3 * 128 + c);
        acc.x += (v0.x + v1.x) + (v2.x + v3.x);
        acc.y += (v0.y + v1.y) + (v2.y + v3.y);
        acc.z += (v0.z + v1.z) + (v2.z + v3.z);
        acc.w += (v0.w + v1.w) + (v2.w + v3.w);
    }
    for (; j < r1; j += 2) {
        int s = csr[j];
        float4 v = *(const float4*)(hWs + (size_t)s * 128 + c);
        acc.x += v.x; acc.y += v.y; acc.z += v.z; acc.w += v.w;
    }
    // combine halves (both halves end with the full sum)
    acc.x += __shfl_xor(acc.x, 32, 64);
    acc.y += __shfl_xor(acc.y, 32, 64);
    acc.z += __shfl_xor(acc.z, 32, 64);
    acc.w += __shfl_xor(acc.w, 32, 64);
    if (lane < 32) {
        float dd = dinv[d];
        float4 vd = *(const float4*)(hWs + (size_t)d * 128 + c);
        float4 bb = *(const float4*)(b + c);
        float4 o;
        o.x = fmaxf(fmaf(acc.x + vd.x, dd, bb.x), 0.f);
        o.y = fmaxf(fmaf(acc.y + vd.y, dd, bb.y), 0.f);
        o.z = fmaxf(fmaf(acc.z + vd.z, dd, bb.z), 0.f);
        o.w = fmaxf(fmaf(acc.w + vd.w, dd, bb.w), 0.f);
        *(float4*)(h1 + (size_t)d * 128 + c) = o;
    }
}

// SAGE gather: mean[d] = (Σ_s h1[s]) * icnt[d]   (same pairing scheme)
__global__ __launch_bounds__(256)
void sage_gather(const int* __restrict__ rowptr, const int* __restrict__ csr,
                 const float* __restrict__ icnt, const float* __restrict__ h1,
                 float* __restrict__ mean, int n)
{
    int d = blockIdx.x * 4 + (threadIdx.x >> 6);
    if (d >= n) return;
    int lane = threadIdx.x & 63;
    int half = lane >> 5;
    int c = (lane & 31) << 2;
    int r0 = rowptr[d], r1 = rowptr[d + 1];
    float4 acc = make_float4(0.f, 0.f, 0.f, 0.f);
    int j = r0 + half;
    for (; j + 6 < r1; j += 8) {
        int s0 = csr[j], s1 = csr[j + 2], s2 = csr[j + 4], s3 = csr[j + 6];
        float4 v0 = *(const float4*)(h1 + (size_t)s0 * 128 + c);
        float4 v1 = *(const float4*)(h1 + (size_t)s1 * 128 + c);
        float4 v2 = *(const float4*)(h1 + (size_t)s2 * 128 + c);
        float4 v3 = *(const float4*)(h1 + (size_t)s3 * 128 + c);
        acc.x += (v0.x + v1.x) + (v2.x + v3.x);
        acc.y += (v0.y + v1.y) + (v2.y + v3.y);
        acc.z += (v0.z + v1.z) + (v2.z + v3.z);
        acc.w += (v0.w + v1.w) + (v2.w + v3.w);
    }
    for (; j < r1; j += 2) {
        int s = csr[j];
        float4 v = *(const float4*)(h1 + (size_t)s * 128 + c);
        acc.x += v.x; acc.y += v.y; acc.z += v.z; acc.w += v.w;
    }
    acc.x += __shfl_xor(acc.x, 32, 64);
    acc.y += __shfl_xor(acc.y, 32, 64);
    acc.z += __shfl_xor(acc.z, 32, 64);
    acc.w += __shfl_xor(acc.w, 32, 64);
    if (lane < 32) {
        float ic = icnt[d];
        float4 o;
        o.x = acc.x * ic; o.y = acc.y * ic; o.z = acc.z * ic; o.w = acc.w * ic;
        *(float4*)(mean + (size_t)d * 128 + c) = o;
    }
}

// ---------------------------------------------------------------------------
// GAT fused single pass: logits are O(1) (att 0.1-scale vs unit features), so
// exp without max-shift is safe and algebraically identical after
// normalization. acc += exp(leaky(al))*xW[s]; wsum += exp; normalize at end.
// Then head-mean + bias + relu + fused out = h3 @ W_out + b_out.
__global__ __launch_bounds__(256)
void gat_gather(const int* __restrict__ rowptr, const int* __restrict__ csr,
                const float* __restrict__ a_s, const float* __restrict__ a_d,
                const float* __restrict__ xW, const float* __restrict__ b_gat,
                const float* __restrict__ W_out, const float* __restrict__ b_out,
                float* __restrict__ out, int n)
{
    __shared__ float h3row[4][128];
    int wv = threadIdx.x >> 6;
    int d = blockIdx.x * 4 + wv;
    if (d >= n) return;
    int lane = threadIdx.x & 63;
    const bool hi = lane >= 32;
    const int hoff = hi ? 1 : 0;
    int r0 = rowptr[d], r1 = rowptr[d + 1];
    const float adh = a_d[d * 2 + hoff];

    // self-loop seed
    float wsum = __expf(leaky02(a_s[d * 2 + hoff] + adh));
    float4 vself = ((const float4*)(xW + (size_t)d * 256))[lane];
    float4 acc;
    acc.x = vself.x * wsum; acc.y = vself.y * wsum;
    acc.z = vself.z * wsum; acc.w = vself.w * wsum;

    int j = r0;
    for (; j + 4 <= r1; j += 4) {
        int e0 = csr[j], e1 = csr[j + 1], e2 = csr[j + 2], e3 = csr[j + 3];
        float av0 = a_s[e0 * 2 + hoff], av1 = a_s[e1 * 2 + hoff];
        float av2 = a_s[e2 * 2 + hoff], av3 = a_s[e3 * 2 + hoff];
        float4 v0 = ((const float4*)(xW + (size_t)e0 * 256))[lane];
        float4 v1 = ((const float4*)(xW + (size_t)e1 * 256))[lane];
        float4 v2 = ((const float4*)(xW + (size_t)e2 * 256))[lane];
        float4 v3 = ((const float4*)(xW + (size_t)e3 * 256))[lane];
        float w0 = __expf(leaky02(av0 + adh));
        float w1 = __expf(leaky02(av1 + adh));
        float w2 = __expf(leaky02(av2 + adh));
        float w3 = __expf(leaky02(av3 + adh));
        wsum += (w0 + w1) + (w2 + w3);
        acc.x = fmaf(v0.x, w0, fmaf(v1.x, w1, fmaf(v2.x, w2, fmaf(v3.x, w3, acc.x))));
        acc.y = fmaf(v0.y, w0, fmaf(v1.y, w1, fmaf(v2.y, w2, fmaf(v3.y, w3, acc.y))));
        acc.z = fmaf(v0.z, w0, fmaf(v1.z, w1, fmaf(v2.z, w2, fmaf(v3.z, w3, acc.z))));
        acc.w = fmaf(v0.w, w0, fmaf(v1.w, w1, fmaf(v2.w, w2, fmaf(v3.w, w3, acc.w))));
    }
    for (; j < r1; ++j) {
        int s = csr[j];
        float w = __expf(leaky02(a_s[s * 2 + hoff] + adh));
        float4 v = ((const float4*)(xW + (size_t)s * 256))[lane];
        wsum += w;
        acc.x = fmaf(v.x, w, acc.x);
        acc.y = fmaf(v.y, w, acc.y);
        acc.z = fmaf(v.z, w, acc.z);
        acc.w = fmaf(v.w, w, acc.w);
    }
    float inv = 1.f / (wsum + 1e-16f);
    acc.x *= inv; acc.y *= inv; acc.z *= inv; acc.w *= inv;

    // head-mean + bias + relu -> h3 row in LDS
    float c0 = acc.x + __shfl_xor(acc.x, 32, 64);
    float c1 = acc.y + __shfl_xor(acc.y, 32, 64);
    float c2 = acc.z + __shfl_xor(acc.z, 32, 64);
    float c3 = acc.w + __shfl_xor(acc.w, 32, 64);
    if (lane < 32) {
        float4 bb = ((const float4*)b_gat)[lane];
        float4 o;
        o.x = fmaxf(0.5f * c0 + bb.x, 0.f);
        o.y = fmaxf(0.5f * c1 + bb.y, 0.f);
        o.z = fmaxf(0.5f * c2 + bb.z, 0.f);
        o.w = fmaxf(0.5f * c3 + bb.w, 0.f);
        ((float4*)h3row[wv])[lane] = o;
    }
    __threadfence_block();
    // fused out layer: out[d, lane] = <h3row, W_out[:,lane]> + b_out[lane]
    const float* hr = h3row[wv];
    float t0 = 0.f, t1 = 0.f, t2 = 0.f, t3 = 0.f;
#pragma unroll 8
    for (int k = 0; k < 128; k += 4) {
        t0 = fmaf(hr[k + 0], W_out[(k + 0) * 64 + lane], t0);
        t1 = fmaf(hr[k + 1], W_out[(k + 1) * 64 + lane], t1);
        t2 = fmaf(hr[k + 2], W_out[(k + 2) * 64 + lane], t2);
        t3 = fmaf(hr[k + 3], W_out[(k + 3) * 64 + lane], t3);
    }
    out[(size_t)d * 64 + lane] = (t0 + t1) + (t2 + t3) + b_out[lane];
}

// ---------------------------------------------------------------------------
extern "C" void kernel_launch(void* const* d_in, const int* in_sizes, int n_in,
                              void* d_out, int out_size, void* d_ws, size_t ws_size,
                              hipStream_t stream)
{
    const float* x      = (const float*)d_in[0];
    const int*   ei     = (const int*)d_in[1];
    const int*   nidx   = (const int*)d_in[2];
    const float* emb    = (const float*)d_in[3];
    const float* W_gcn  = (const float*)d_in[4];
    const float* b_gcn  = (const float*)d_in[5];
    const float* W_sl   = (const float*)d_in[6];
    const float* W_sr   = (const float*)d_in[7];
    const float* b_sage = (const float*)d_in[8];
    const float* W_gat  = (const float*)d_in[9];
    const float* att_s  = (const float*)d_in[10];
    const float* att_d  = (const float*)d_in[11];
    const float* b_gat  = (const float*)d_in[12];
    const float* W_out  = (const float*)d_in[13];
    const float* b_out  = (const float*)d_in[14];
    float* out = (float*)d_out;

    const int n = in_sizes[0] / 128;
    const int E = in_sizes[1] / 2;
    const int* esrc = ei;
    const int* edst = ei + E;

    const size_t P = (size_t)n * 128;
    const int nb_scan = (n + 1023) / 1024;
    float* ws   = (float*)d_ws;
    float* bufA = ws;                 // hWs -> mean
    float* h1   = ws + P;
    float* h2   = ws + 2 * P;
    float* xW   = ws + 3 * P;         // 2P
    float* dinv = ws + 5 * P;         // n
    float* icnt = dinv + n;           // n
    float* a_s  = icnt + n;           // 2n
    float* a_d  = a_s + 2 * n;        // 2n
    int* degi   = (int*)(a_d + 2 * n);// n  \ zeroed by one memset
    int* fill   = degi + n;           // n  /
    int* rowptr = fill + n;           // n+1
    int* partial= rowptr + n + 1;     // nb_scan
    int* csr    = partial + nb_scan + 1;  // E

    const int TB = 256;
    int nblk_n     = (n + TB - 1) / TB;
    int nblk_e     = (E + TB - 1) / TB;
    int nblk_wav_n = (n + 3) / 4;
    int gemm_rows  = (n + 127) / 128;

    // --- degrees + CSR build ---
    hipMemsetAsync(degi, 0, 2 * (size_t)n * sizeof(int), stream);   // degi+fill
    deg_edges<<<nblk_e, TB, 0, stream>>>(edst, degi, E);
    scan_part_norm<<<nb_scan, TB, 0, stream>>>(degi, partial, dinv, icnt, n);
    scan_offsets<<<1, 64, 0, stream>>>(partial, nb_scan);
    scan_write<<<nb_scan, TB, 0, stream>>>(degi, partial, rowptr, n);
    csr_fill<<<nblk_e, TB, 0, stream>>>(esrc, edst, rowptr, fill, csr, E);

    // --- GCN: hWs = (x@Wg_top + emb@Wg_bot) * dinv[row] ---
    gemm_k128<true, false, false, true, true, false><<<dim3(gemm_rows, 1), TB, 0, stream>>>(
        x, W_gcn, emb, W_gcn + 128 * 128, nidx, nullptr, dinv,
        nullptr, nullptr, nullptr, nullptr, bufA, n, 128, 128);
    gcn_gather<<<nblk_wav_n, TB, 0, stream>>>(rowptr, csr, dinv, bufA, b_gcn, h1, n);

    // --- SAGE ---
    sage_gather<<<nblk_wav_n, TB, 0, stream>>>(rowptr, csr, icnt, h1, bufA, n);
    gemm_k128<true, true, true, false, false, false><<<dim3(gemm_rows, 1), TB, 0, stream>>>(
        bufA, W_sl, h1, W_sr, nullptr, b_sage, nullptr,
        nullptr, nullptr, nullptr, nullptr, h2, n, 128, 128);

    // --- GAT: xW + fused attention logits ---
    gemm_k128<false, false, false, false, false, true><<<dim3(gemm_rows, 2), TB, 0, stream>>>(
        h2, W_gat, nullptr, nullptr, nullptr, nullptr, nullptr,
        att_s, att_d, a_s, a_d, xW, n, 256, 256);
    gat_gather<<<nblk_wav_n, TB, 0, stream>>>(rowptr, csr, a_s, a_d, xW, b_gat,
                                              W_out, b_out, out, n);
}

// Round 5
// 729.765 us; speedup vs baseline: 12.0246x; 1.1865x over previous
//
#include <hip/hip_runtime.h>

// ---------------------------------------------------------------------------
// StructuralGNN: GCN -> SAGE -> GAT(2 heads) -> Linear on N=50k, E=1.6M, D=128
// Round 5: gathered feature tables stored as bf16 (RNE) -> halves the L2-miss
// bytes of the three edge gathers (the measured bottleneck: FETCH_SIZE ~800MB
// vs 51MB table => L2 thrash at ~3.5 TB/s fill rate). All GEMM math fp32.
// ---------------------------------------------------------------------------

static __device__ __forceinline__ float leaky02(float x) {
    return x > 0.f ? x : 0.2f * x;
}
static __device__ __forceinline__ unsigned short f2bf(float f) {
    unsigned u = __float_as_uint(f);
    u = (u + 0x7FFFu + ((u >> 16) & 1u)) >> 16;   // RNE
    return (unsigned short)u;
}
static __device__ __forceinline__ float bf2f(unsigned short h) {
    return __uint_as_float(((unsigned)h) << 16);
}
static __device__ __forceinline__ float4 bf4(ushort4 h) {
    return make_float4(bf2f(h.x), bf2f(h.y), bf2f(h.z), bf2f(h.w));
}

// ---------------------------------------------------------------------------
__global__ void deg_edges(const int* __restrict__ dst, int* __restrict__ degi, int E) {
    int e = blockIdx.x * blockDim.x + threadIdx.x;
    if (e < E) atomicAdd(&degi[dst[e]], 1);
}

// per-1024-chunk sums of edge counts + dinv/icnt computation
__global__ __launch_bounds__(256)
void scan_part_norm(const int* __restrict__ degi, int* __restrict__ partial,
                    float* __restrict__ dinv, float* __restrict__ icnt, int n)
{
    int t = threadIdx.x;
    int base = blockIdx.x * 1024 + t * 4;
    int s = 0;
#pragma unroll
    for (int i = 0; i < 4; ++i) {
        int g = base + i;
        if (g < n) {
            int de = degi[g];                    // in-edges (no self)
            s += de;
            dinv[g] = rsqrtf((float)(de + 1));   // GCN deg includes self loop
            icnt[g] = 1.0f / (float)(de > 1 ? de : 1);
        }
    }
#pragma unroll
    for (int m = 32; m > 0; m >>= 1) s += __shfl_xor(s, m, 64);
    __shared__ int wsum[4];
    if ((t & 63) == 0) wsum[t >> 6] = s;
    __syncthreads();
    if (t == 0) partial[blockIdx.x] = wsum[0] + wsum[1] + wsum[2] + wsum[3];
}

// single wave scans chunk sums -> exclusive offsets
__global__ __launch_bounds__(64)
void scan_offsets(int* __restrict__ partial, int nb)
{
    int t = threadIdx.x;
    int carry = 0;
    for (int base = 0; base < nb; base += 64) {
        int i = base + t;
        int v = (i < nb) ? partial[i] : 0;
        int incl = v;
#pragma unroll
        for (int m = 1; m < 64; m <<= 1) {
            int o = __shfl_up(incl, m, 64);
            if (t >= m) incl += o;
        }
        if (i < nb) partial[i] = incl - v + carry;
        carry += __shfl(incl, 63, 64);
    }
}

// per-chunk exclusive scan + chunk offset -> rowptr
__global__ __launch_bounds__(256)
void scan_write(const int* __restrict__ degi, const int* __restrict__ partial,
                int* __restrict__ rowptr, int n)
{
    __shared__ int tmp[256];
    int t = threadIdx.x;
    int base = blockIdx.x * 1024 + t * 4;
    int v[4]; int s = 0;
#pragma unroll
    for (int i = 0; i < 4; ++i) {
        int g = base + i;
        v[i] = (g < n) ? degi[g] : 0;
        s += v[i];
    }
    tmp[t] = s;
    __syncthreads();
    for (int off = 1; off < 256; off <<= 1) {
        int a = (t >= off) ? tmp[t - off] : 0;
        __syncthreads();
        tmp[t] += a;
        __syncthreads();
    }
    int run = tmp[t] - s + partial[blockIdx.x];
#pragma unroll
    for (int i = 0; i < 4; ++i) {
        int g = base + i;
        run += v[i];
        if (g < n) rowptr[g + 1] = run;
    }
    if (blockIdx.x == 0 && t == 0) rowptr[0] = 0;
}

__global__ void csr_fill(const int* __restrict__ src, const int* __restrict__ dst,
                         const int* __restrict__ rowptr, int* __restrict__ fill,
                         int* __restrict__ csr, int E)
{
    int e = blockIdx.x * blockDim.x + threadIdx.x;
    if (e >= E) return;
    int d = dst[e];
    int pos = rowptr[d] + atomicAdd(&fill[d], 1);
    csr[pos] = src[e];
}

// ---------------------------------------------------------------------------
// C[128-row tile x 128-col slice] = act( scale*(A1@W1 + A2[idx]@W2) + bias )
// 256 threads, 8x8 micro-tile. Optional attention-logit epilogue; optional
// bf16-packed output.
template<bool HAS_A2, bool RELU, bool HAS_BIAS, bool HAS_IDX, bool SCALE,
         bool ATT, bool OUT_BF16>
__global__ __launch_bounds__(256)
void gemm_k128(const float* __restrict__ A1, const float* __restrict__ W1,
               const float* __restrict__ A2, const float* __restrict__ W2,
               const int* __restrict__ idx2, const float* __restrict__ bias,
               const float* __restrict__ scale,
               const float* __restrict__ att_src, const float* __restrict__ att_dst,
               float* __restrict__ a_s, float* __restrict__ a_d,
               float* __restrict__ C, int nrows, int ncW, int ncC)
{
    __shared__ float As[128][33];
    __shared__ float Ws[32][128];
    const int t = threadIdx.x;
    const int tc = t & 15;        // 16 col groups * 8 cols
    const int tr = t >> 4;        // 16 row groups * 8 rows
    const int row0 = blockIdx.x * 128;
    const int colOff = blockIdx.y * 128;

    float acc[8][8] = {};

    const int npass = HAS_A2 ? 2 : 1;
    for (int p = 0; p < npass; ++p) {
        const float* A = (p == 0) ? A1 : A2;
        const float* W = (p == 0) ? W1 : W2;
        for (int kt = 0; kt < 4; ++kt) {
#pragma unroll
            for (int i = 0; i < 4; ++i) {       // stage A: 128 x 32
                int f = i * 256 + t;
                int r = f >> 3, c4 = (f & 7) << 2;
                int row = row0 + r; if (row >= nrows) row = nrows - 1;
                int arow = (p == 1 && HAS_IDX) ? idx2[row] : row;
                float4 v = *(const float4*)(A + (size_t)arow * 128 + kt * 32 + c4);
                As[r][c4 + 0] = v.x; As[r][c4 + 1] = v.y;
                As[r][c4 + 2] = v.z; As[r][c4 + 3] = v.w;
            }
#pragma unroll
            for (int i = 0; i < 4; ++i) {       // stage W: 32 x 128
                int f = i * 256 + t;
                int wr = f >> 5, wc4 = (f & 31) << 2;
                *(float4*)&Ws[wr][wc4] =
                    *(const float4*)(W + (size_t)(kt * 32 + wr) * ncW + colOff + wc4);
            }
            __syncthreads();
#pragma unroll
            for (int kk = 0; kk < 32; ++kk) {
                float a[8], w[8];
#pragma unroll
                for (int i = 0; i < 8; ++i) a[i] = As[tr * 8 + i][kk];
#pragma unroll
                for (int j = 0; j < 8; ++j) w[j] = Ws[kk][tc * 8 + j];
#pragma unroll
                for (int i = 0; i < 8; ++i)
#pragma unroll
                    for (int j = 0; j < 8; ++j)
                        acc[i][j] = fmaf(a[i], w[j], acc[i][j]);
            }
            __syncthreads();
        }
    }

    float as_v[8], ad_v[8];
    if (ATT) {
#pragma unroll
        for (int j = 0; j < 8; ++j) {
            as_v[j] = att_src[colOff + tc * 8 + j];
            ad_v[j] = att_dst[colOff + tc * 8 + j];
        }
    }
#pragma unroll
    for (int i = 0; i < 8; ++i) {
        int row = row0 + tr * 8 + i;
        bool ok = row < nrows;
        float sc = 1.f;
        if (SCALE) sc = ok ? scale[row] : 0.f;
        float vv[8];
#pragma unroll
        for (int j = 0; j < 8; ++j) {
            float v = acc[i][j];
            if (SCALE) v *= sc;
            if (HAS_BIAS) v += bias[colOff + tc * 8 + j];
            if (RELU) v = fmaxf(v, 0.f);
            vv[j] = v;
        }
        if (ok) {
            if (OUT_BF16) {
                unsigned short* cp =
                    (unsigned short*)C + (size_t)row * ncC + colOff + tc * 8;
                uint4 pk;
                pk.x = (unsigned)f2bf(vv[0]) | ((unsigned)f2bf(vv[1]) << 16);
                pk.y = (unsigned)f2bf(vv[2]) | ((unsigned)f2bf(vv[3]) << 16);
                pk.z = (unsigned)f2bf(vv[4]) | ((unsigned)f2bf(vv[5]) << 16);
                pk.w = (unsigned)f2bf(vv[6]) | ((unsigned)f2bf(vv[7]) << 16);
                *(uint4*)cp = pk;
            } else {
                float* cp = C + (size_t)row * ncC + colOff + tc * 8;
                *(float4*)cp = make_float4(vv[0], vv[1], vv[2], vv[3]);
                *(float4*)(cp + 4) = make_float4(vv[4], vv[5], vv[6], vv[7]);
            }
        }
        if (ATT) {
            float ps = 0.f, pd = 0.f;
#pragma unroll
            for (int j = 0; j < 8; ++j) {
                ps = fmaf(vv[j], as_v[j], ps);
                pd = fmaf(vv[j], ad_v[j], pd);
            }
#pragma unroll
            for (int m = 1; m < 16; m <<= 1) {
                ps += __shfl_xor(ps, m, 64);
                pd += __shfl_xor(pd, m, 64);
            }
            if (ok && tc == 0) {
                a_s[row * 2 + blockIdx.y] = ps;
                a_d[row * 2 + blockIdx.y] = pd;
            }
        }
    }
}

// ---------------------------------------------------------------------------
// GCN gather over bf16 hWs (pre-scaled by dinv[src]). Paired edges: lanes
// 0-31 even edges, 32-63 odd; combine via shfl_xor(32).
// h1[d] = relu(dinv[d]*(sum_s hWs[s] + hWs[d]) + b); writes fp32 + bf16 copy.
__global__ __launch_bounds__(256)
void gcn_gather(const int* __restrict__ rowptr, const int* __restrict__ csr,
                const float* __restrict__ dinv,
                const unsigned short* __restrict__ hWb,
                const float* __restrict__ b, float* __restrict__ h1,
                unsigned short* __restrict__ h1b, int n)
{
    int d = blockIdx.x * 4 + (threadIdx.x >> 6);
    if (d >= n) return;
    int lane = threadIdx.x & 63;
    int half = lane >> 5;
    int c = (lane & 31) << 2;      // column group (4 elems)
    int r0 = rowptr[d], r1 = rowptr[d + 1];
    float4 acc = make_float4(0.f, 0.f, 0.f, 0.f);
    int j = r0 + half;
    for (; j + 6 < r1; j += 8) {
        int s0 = csr[j], s1 = csr[j + 2], s2 = csr[j + 4], s3 = csr[j + 6];
        float4 v0 = bf4(*(const ushort4*)(hWb + (size_t)s0 * 128 + c));
        float4 v1 = bf4(*(const ushort4*)(hWb + (size_t)s1 * 128 + c));
        float4 v2 = bf4(*(const ushort4*)(hWb + (size_t)s2 * 128 + c));
        float4 v3 = bf4(*(const ushort4*)(hWb + (size_t)s3 * 128 + c));
        acc.x += (v0.x + v1.x) + (v2.x + v3.x);
        acc.y += (v0.y + v1.y) + (v2.y + v3.y);
        acc.z += (v0.z + v1.z) + (v2.z + v3.z);
        acc.w += (v0.w + v1.w) + (v2.w + v3.w);
    }
    for (; j < r1; j += 2) {
        int s = csr[j];
        float4 v = bf4(*(const ushort4*)(hWb + (size_t)s * 128 + c));
        acc.x += v.x; acc.y += v.y; acc.z += v.z; acc.w += v.w;
    }
    acc.x += __shfl_xor(acc.x, 32, 64);
    acc.y += __shfl_xor(acc.y, 32, 64);
    acc.z += __shfl_xor(acc.z, 32, 64);
    acc.w += __shfl_xor(acc.w, 32, 64);
    if (lane < 32) {
        float dd = dinv[d];
        float4 vd = bf4(*(const ushort4*)(hWb + (size_t)d * 128 + c));
        float4 bb = *(const float4*)(b + c);
        float4 o;
        o.x = fmaxf(fmaf(acc.x + vd.x, dd, bb.x), 0.f);
        o.y = fmaxf(fmaf(acc.y + vd.y, dd, bb.y), 0.f);
        o.z = fmaxf(fmaf(acc.z + vd.z, dd, bb.z), 0.f);
        o.w = fmaxf(fmaf(acc.w + vd.w, dd, bb.w), 0.f);
        *(float4*)(h1 + (size_t)d * 128 + c) = o;
        ushort4 p;
        p.x = f2bf(o.x); p.y = f2bf(o.y); p.z = f2bf(o.z); p.w = f2bf(o.w);
        *(ushort4*)(h1b + (size_t)d * 128 + c) = p;
    }
}

// SAGE gather over bf16 h1: mean[d] = (sum_s h1[s]) * icnt[d]  (fp32 out)
__global__ __launch_bounds__(256)
void sage_gather(const int* __restrict__ rowptr, const int* __restrict__ csr,
                 const float* __restrict__ icnt,
                 const unsigned short* __restrict__ h1b,
                 float* __restrict__ mean, int n)
{
    int d = blockIdx.x * 4 + (threadIdx.x >> 6);
    if (d >= n) return;
    int lane = threadIdx.x & 63;
    int half = lane >> 5;
    int c = (lane & 31) << 2;
    int r0 = rowptr[d], r1 = rowptr[d + 1];
    float4 acc = make_float4(0.f, 0.f, 0.f, 0.f);
    int j = r0 + half;
    for (; j + 6 < r1; j += 8) {
        int s0 = csr[j], s1 = csr[j + 2], s2 = csr[j + 4], s3 = csr[j + 6];
        float4 v0 = bf4(*(const ushort4*)(h1b + (size_t)s0 * 128 + c));
        float4 v1 = bf4(*(const ushort4*)(h1b + (size_t)s1 * 128 + c));
        float4 v2 = bf4(*(const ushort4*)(h1b + (size_t)s2 * 128 + c));
        float4 v3 = bf4(*(const ushort4*)(h1b + (size_t)s3 * 128 + c));
        acc.x += (v0.x + v1.x) + (v2.x + v3.x);
        acc.y += (v0.y + v1.y) + (v2.y + v3.y);
        acc.z += (v0.z + v1.z) + (v2.z + v3.z);
        acc.w += (v0.w + v1.w) + (v2.w + v3.w);
    }
    for (; j < r1; j += 2) {
        int s = csr[j];
        float4 v = bf4(*(const ushort4*)(h1b + (size_t)s * 128 + c));
        acc.x += v.x; acc.y += v.y; acc.z += v.z; acc.w += v.w;
    }
    acc.x += __shfl_xor(acc.x, 32, 64);
    acc.y += __shfl_xor(acc.y, 32, 64);
    acc.z += __shfl_xor(acc.z, 32, 64);
    acc.w += __shfl_xor(acc.w, 32, 64);
    if (lane < 32) {
        float ic = icnt[d];
        float4 o;
        o.x = acc.x * ic; o.y = acc.y * ic; o.z = acc.z * ic; o.w = acc.w * ic;
        *(float4*)(mean + (size_t)d * 128 + c) = o;
    }
}

// ---------------------------------------------------------------------------
// GAT fused single pass over bf16 xW (logits O(1) => exp w/o max-shift is
// exact after normalization): acc += exp(leaky(al))*xW[s]; wsum += exp;
// normalize; head-mean + bias + relu; fused out = h3 @ W_out + b_out.
__global__ __launch_bounds__(256)
void gat_gather(const int* __restrict__ rowptr, const int* __restrict__ csr,
                const float* __restrict__ a_s, const float* __restrict__ a_d,
                const unsigned short* __restrict__ xWb,
                const float* __restrict__ b_gat,
                const float* __restrict__ W_out, const float* __restrict__ b_out,
                float* __restrict__ out, int n)
{
    __shared__ float h3row[4][128];
    int wv = threadIdx.x >> 6;
    int d = blockIdx.x * 4 + wv;
    if (d >= n) return;
    int lane = threadIdx.x & 63;
    const bool hi = lane >= 32;
    const int hoff = hi ? 1 : 0;
    int r0 = rowptr[d], r1 = rowptr[d + 1];
    const float adh = a_d[d * 2 + hoff];

    // self-loop seed
    float wsum = __expf(leaky02(a_s[d * 2 + hoff] + adh));
    float4 vself = bf4(((const ushort4*)(xWb + (size_t)d * 256))[lane]);
    float4 acc;
    acc.x = vself.x * wsum; acc.y = vself.y * wsum;
    acc.z = vself.z * wsum; acc.w = vself.w * wsum;

    int j = r0;
    for (; j + 4 <= r1; j += 4) {
        int e0 = csr[j], e1 = csr[j + 1], e2 = csr[j + 2], e3 = csr[j + 3];
        float av0 = a_s[e0 * 2 + hoff], av1 = a_s[e1 * 2 + hoff];
        float av2 = a_s[e2 * 2 + hoff], av3 = a_s[e3 * 2 + hoff];
        float4 v0 = bf4(((const ushort4*)(xWb + (size_t)e0 * 256))[lane]);
        float4 v1 = bf4(((const ushort4*)(xWb + (size_t)e1 * 256))[lane]);
        float4 v2 = bf4(((const ushort4*)(xWb + (size_t)e2 * 256))[lane]);
        float4 v3 = bf4(((const ushort4*)(xWb + (size_t)e3 * 256))[lane]);
        float w0 = __expf(leaky02(av0 + adh));
        float w1 = __expf(leaky02(av1 + adh));
        float w2 = __expf(leaky02(av2 + adh));
        float w3 = __expf(leaky02(av3 + adh));
        wsum += (w0 + w1) + (w2 + w3);
        acc.x = fmaf(v0.x, w0, fmaf(v1.x, w1, fmaf(v2.x, w2, fmaf(v3.x, w3, acc.x))));
        acc.y = fmaf(v0.y, w0, fmaf(v1.y, w1, fmaf(v2.y, w2, fmaf(v3.y, w3, acc.y))));
        acc.z = fmaf(v0.z, w0, fmaf(v1.z, w1, fmaf(v2.z, w2, fmaf(v3.z, w3, acc.z))));
        acc.w = fmaf(v0.w, w0, fmaf(v1.w, w1, fmaf(v2.w, w2, fmaf(v3.w, w3, acc.w))));
    }
    for (; j < r1; ++j) {
        int s = csr[j];
        float w = __expf(leaky02(a_s[s * 2 + hoff] + adh));
        float4 v = bf4(((const ushort4*)(xWb + (size_t)s * 256))[lane]);
        wsum += w;
        acc.x = fmaf(v.x, w, acc.x);
        acc.y = fmaf(v.y, w, acc.y);
        acc.z = fmaf(v.z, w, acc.z);
        acc.w = fmaf(v.w, w, acc.w);
    }
    float inv = 1.f / (wsum + 1e-16f);
    acc.x *= inv; acc.y *= inv; acc.z *= inv; acc.w *= inv;

    // head-mean + bias + relu -> h3 row in LDS
    float c0 = acc.x + __shfl_xor(acc.x, 32, 64);
    float c1 = acc.y + __shfl_xor(acc.y, 32, 64);
    float c2 = acc.z + __shfl_xor(acc.z, 32, 64);
    float c3 = acc.w + __shfl_xor(acc.w, 32, 64);
    if (lane < 32) {
        float4 bb = ((const float4*)b_gat)[lane];
        float4 o;
        o.x = fmaxf(0.5f * c0 + bb.x, 0.f);
        o.y = fmaxf(0.5f * c1 + bb.y, 0.f);
        o.z = fmaxf(0.5f * c2 + bb.z, 0.f);
        o.w = fmaxf(0.5f * c3 + bb.w, 0.f);
        ((float4*)h3row[wv])[lane] = o;
    }
    __threadfence_block();
    // fused out layer: out[d, lane] = <h3row, W_out[:,lane]> + b_out[lane]
    const float* hr = h3row[wv];
    float t0 = 0.f, t1 = 0.f, t2 = 0.f, t3 = 0.f;
#pragma unroll 8
    for (int k = 0; k < 128; k += 4) {
        t0 = fmaf(hr[k + 0], W_out[(k + 0) * 64 + lane], t0);
        t1 = fmaf(hr[k + 1], W_out[(k + 1) * 64 + lane], t1);
        t2 = fmaf(hr[k + 2], W_out[(k + 2) * 64 + lane], t2);
        t3 = fmaf(hr[k + 3], W_out[(k + 3) * 64 + lane], t3);
    }
    out[(size_t)d * 64 + lane] = (t0 + t1) + (t2 + t3) + b_out[lane];
}

// ---------------------------------------------------------------------------
extern "C" void kernel_launch(void* const* d_in, const int* in_sizes, int n_in,
                              void* d_out, int out_size, void* d_ws, size_t ws_size,
                              hipStream_t stream)
{
    const float* x      = (const float*)d_in[0];
    const int*   ei     = (const int*)d_in[1];
    const int*   nidx   = (const int*)d_in[2];
    const float* emb    = (const float*)d_in[3];
    const float* W_gcn  = (const float*)d_in[4];
    const float* b_gcn  = (const float*)d_in[5];
    const float* W_sl   = (const float*)d_in[6];
    const float* W_sr   = (const float*)d_in[7];
    const float* b_sage = (const float*)d_in[8];
    const float* W_gat  = (const float*)d_in[9];
    const float* att_s  = (const float*)d_in[10];
    const float* att_d  = (const float*)d_in[11];
    const float* b_gat  = (const float*)d_in[12];
    const float* W_out  = (const float*)d_in[13];
    const float* b_out  = (const float*)d_in[14];
    float* out = (float*)d_out;

    const int n = in_sizes[0] / 128;
    const int E = in_sizes[1] / 2;
    const int* esrc = ei;
    const int* edst = ei + E;

    const size_t P = (size_t)n * 128;
    const int nb_scan = (n + 1023) / 1024;
    float* ws   = (float*)d_ws;
    float* mean = ws;                 // P fp32 (SAGE GEMM A1)
    float* h1   = ws + P;             // P fp32 (SAGE GEMM A2)
    float* h2   = ws + 2 * P;         // P fp32 (GAT GEMM A1)
    unsigned short* hWb = (unsigned short*)(ws + 3 * P);          // P bf16
    unsigned short* h1b = (unsigned short*)(ws + 3 * P + P / 2);  // P bf16
    unsigned short* xWb = (unsigned short*)(ws + 4 * P);          // 2P bf16
    float* dinv = ws + 5 * P;         // n
    float* icnt = dinv + n;           // n
    float* a_s  = icnt + n;           // 2n
    float* a_d  = a_s + 2 * n;        // 2n
    int* degi   = (int*)(a_d + 2 * n);// n  \ zeroed by one memset
    int* fill   = degi + n;           // n  /
    int* rowptr = fill + n;           // n+1
    int* partial= rowptr + n + 1;     // nb_scan
    int* csr    = partial + nb_scan + 1;  // E

    const int TB = 256;
    int nblk_e     = (E + TB - 1) / TB;
    int nblk_wav_n = (n + 3) / 4;
    int gemm_rows  = (n + 127) / 128;

    // --- degrees + CSR build ---
    hipMemsetAsync(degi, 0, 2 * (size_t)n * sizeof(int), stream);   // degi+fill
    deg_edges<<<nblk_e, TB, 0, stream>>>(edst, degi, E);
    scan_part_norm<<<nb_scan, TB, 0, stream>>>(degi, partial, dinv, icnt, n);
    scan_offsets<<<1, 64, 0, stream>>>(partial, nb_scan);
    scan_write<<<nb_scan, TB, 0, stream>>>(degi, partial, rowptr, n);
    csr_fill<<<nblk_e, TB, 0, stream>>>(esrc, edst, rowptr, fill, csr, E);

    // --- GCN: hWb = bf16( (x@Wg_top + emb@Wg_bot) * dinv[row] ) ---
    gemm_k128<true, false, false, true, true, false, true>
        <<<dim3(gemm_rows, 1), TB, 0, stream>>>(
        x, W_gcn, emb, W_gcn + 128 * 128, nidx, nullptr, dinv,
        nullptr, nullptr, nullptr, nullptr, (float*)hWb, n, 128, 128);
    gcn_gather<<<nblk_wav_n, TB, 0, stream>>>(rowptr, csr, dinv, hWb, b_gcn,
                                              h1, h1b, n);

    // --- SAGE ---
    sage_gather<<<nblk_wav_n, TB, 0, stream>>>(rowptr, csr, icnt, h1b, mean, n);
    gemm_k128<true, true, true, false, false, false, false>
        <<<dim3(gemm_rows, 1), TB, 0, stream>>>(
        mean, W_sl, h1, W_sr, nullptr, b_sage, nullptr,
        nullptr, nullptr, nullptr, nullptr, h2, n, 128, 128);

    // --- GAT: xWb (bf16) + fused attention logits ---
    gemm_k128<false, false, false, false, false, true, true>
        <<<dim3(gemm_rows, 2), TB, 0, stream>>>(
        h2, W_gat, nullptr, nullptr, nullptr, nullptr, nullptr,
        att_s, att_d, a_s, a_d, (float*)xWb, n, 256, 256);
    gat_gather<<<nblk_wav_n, TB, 0, stream>>>(rowptr, csr, a_s, a_d, xWb, b_gat,
                                              W_out, b_out, out, n);
}